// Round 12
// baseline (258.937 us; speedup 1.0000x reference)
//
#include <hip/hip_runtime.h>
#include <math.h>

#define NTOK 16384
#define H 4096
#define NE 256
#define EPS_E 1.2e-5f
#define EPS_G 2.4e-5f
#define FIXCAP 1024
#define FLAGCAP 8192

typedef __attribute__((ext_vector_type(8))) short short8;
typedef __attribute__((ext_vector_type(4))) float f32x4;

__device__ __forceinline__ unsigned short f2bf(float x) {
    union { float f; unsigned u; } v; v.f = x;
    unsigned r = v.u + 0x7FFF + ((v.u >> 16) & 1);
    return (unsigned short)(r >> 16);
}
__device__ __forceinline__ float bf2f(unsigned short h) {
    union { float f; unsigned u; } v; v.u = ((unsigned)h) << 16;
    return v.f;
}

__global__ void zero_ws(int* ws) { if (threadIdx.x == 0) ws[0] = 0; }

__global__ __launch_bounds__(256)
void split_w(const float* __restrict__ W, unsigned short* __restrict__ whi,
             unsigned short* __restrict__ wlo)
{
    const int i = (blockIdx.x * 256 + threadIdx.x) * 4;
    float4 w4 = *(const float4*)(W + i);
    const float wv[4] = {w4.x, w4.y, w4.z, w4.w};
    ushort4 hh, ll;
    unsigned short* hp = (unsigned short*)&hh;
    unsigned short* lp = (unsigned short*)&ll;
    #pragma unroll
    for (int j = 0; j < 4; ++j) {
        unsigned short h = f2bf(wv[j]);
        hp[j] = h;
        lp[j] = f2bf(wv[j] - bf2f(h));
    }
    *(ushort4*)(whi + i) = hh;
    *(ushort4*)(wlo + i) = ll;
}

// ============ Stage 1: BM=64 x BN=256, 4 waves, acc4x4, B-dbuf, 1 block/CU ============
__global__ __launch_bounds__(256, 1)
void gemm3(const float* __restrict__ X, const unsigned short* __restrict__ Whi,
           const unsigned short* __restrict__ Wlo, float* __restrict__ logits,
           int m_base)
{
    __shared__ __align__(16) unsigned short smem[73728];  // 144 KB
    unsigned short* Bh0 = smem;             // [256][64] 32KB
    unsigned short* Bl0 = smem + 16384;
    unsigned short* Bh1 = smem + 32768;
    unsigned short* Bl1 = smem + 49152;
    unsigned short* Ah  = smem + 65536;     // [64][64] XOR-swizzled
    unsigned short* Al  = smem + 69632;

    const int t = threadIdx.x;
    const int lane = t & 63;
    const int w = t >> 6;                   // wave 0..3 -> expert quarter
    const int fr = lane & 15, fq = lane >> 4;
    const int mloc = blockIdx.x * 64;
    const int m0 = m_base + mloc;
    const int e0q = w * 64;

    f32x4 acc[4][4];
    #pragma unroll
    for (int a = 0; a < 4; ++a)
        #pragma unroll
        for (int b = 0; b < 4; ++b) acc[a][b] = (f32x4){0.f, 0.f, 0.f, 0.f};

    // A staging (measured 0 conflicts): row t>>2, 16 floats at chunk t&3
    const int ar = t >> 2;
    const int akc = t & 3;
    const float* gxa = X + (size_t)(m0 + ar) * H + akc * 16;

    // B staging: wave stages its own expert quarter (linear dest, pre-swizzled source)
    const int blr = lane >> 3;
    const int bsrc = (lane & 7) ^ blr;
    const unsigned short* gbh = Whi + (size_t)(e0q + blr) * H + bsrc * 8;
    const unsigned short* gbl = Wlo + (size_t)(e0q + blr) * H + bsrc * 8;

    auto issueB = [&](unsigned short* dh, unsigned short* dl, int kt) {
        const size_t k0 = (size_t)kt * 64;
        #pragma unroll
        for (int i = 0; i < 8; ++i) {
            __builtin_amdgcn_global_load_lds(
                (const __attribute__((address_space(1))) void*)(gbh + (size_t)(8 * i) * H + k0),
                (__attribute__((address_space(3))) void*)&dh[(e0q + 8 * i) * 64], 16, 0, 0);
            __builtin_amdgcn_global_load_lds(
                (const __attribute__((address_space(1))) void*)(gbl + (size_t)(8 * i) * H + k0),
                (__attribute__((address_space(3))) void*)&dl[(e0q + 8 * i) * 64], 16, 0, 0);
        }
    };

    float4 xr0, xr1, xr2, xr3;
    auto loadX = [&](int kt) {
        const float* p = gxa + (size_t)kt * 64;
        xr0 = *(const float4*)p;       xr1 = *(const float4*)(p + 4);
        xr2 = *(const float4*)(p + 8); xr3 = *(const float4*)(p + 12);
    };

    auto step = [&](const unsigned short* Bhc, const unsigned short* Blc,
                    unsigned short* Bhn, unsigned short* Bln, int kt) {
        // a: issue B(kt+1) [16] -> outstanding 36 (B(kt)16 + X(kt)4 + 16)
        issueB(Bhn, Bln, (kt + 1) & 63);
        __builtin_amdgcn_sched_barrier(0);
        // b: drain B(kt)+X(kt); keep B(kt+1) in flight
        asm volatile("s_waitcnt vmcnt(16)" ::: "memory");
        __builtin_amdgcn_sched_barrier(0);
        // c: split X(kt) -> swizzled A LDS write
        {
            const float xf[16] = {xr0.x, xr0.y, xr0.z, xr0.w, xr1.x, xr1.y, xr1.z, xr1.w,
                                  xr2.x, xr2.y, xr2.z, xr2.w, xr3.x, xr3.y, xr3.z, xr3.w};
            short8 h0, h1, l0, l1;
            #pragma unroll
            for (int j = 0; j < 16; ++j) {
                union { float f; unsigned u; } uu; uu.f = xf[j];
                union { unsigned u; float f; } hh; hh.u = uu.u & 0xFFFF0000u;
                union { float f; unsigned u; } ll; ll.f = xf[j] - hh.f;
                unsigned short hs = (unsigned short)(uu.u >> 16);
                unsigned short ls = (unsigned short)(ll.u >> 16);
                if (j < 8) { h0[j] = (short)hs; l0[j] = (short)ls; }
                else       { h1[j - 8] = (short)hs; l1[j - 8] = (short)ls; }
            }
            const int c0 = akc * 2;
            const int p0 = (c0 ^ (ar & 7)) * 8, p1 = ((c0 + 1) ^ (ar & 7)) * 8;
            *(short8*)&Ah[ar * 64 + p0] = h0;
            *(short8*)&Ah[ar * 64 + p1] = h1;
            *(short8*)&Al[ar * 64 + p0] = l0;
            *(short8*)&Al[ar * 64 + p1] = l1;
        }
        // d: prefetch X(kt+1)  [outstanding: B(kt+1)16 + 4 = 20]
        loadX(kt + 1 < 64 ? kt + 1 : 63);
        __builtin_amdgcn_sched_barrier(0);
        // e: A writes visible -> barrier #1
        asm volatile("s_waitcnt lgkmcnt(0)" ::: "memory");
        __builtin_amdgcn_sched_barrier(0);
        __builtin_amdgcn_s_barrier();
        // f: frag reads + 96 MFMA, compiler-interleaved
        short8 ah[2][4], al[2][4], bh[2][4], bl[2][4];
        #pragma unroll
        for (int kk = 0; kk < 2; ++kk) {
            #pragma unroll
            for (int mt = 0; mt < 4; ++mt) {
                const int r = mt * 16 + fr;
                const int pos = ((kk * 4 + fq) ^ (r & 7)) * 8;
                ah[kk][mt] = *(const short8*)&Ah[r * 64 + pos];
                al[kk][mt] = *(const short8*)&Al[r * 64 + pos];
            }
            #pragma unroll
            for (int nt = 0; nt < 4; ++nt) {
                const int r = e0q + nt * 16 + fr;
                const int pos = ((kk * 4 + fq) ^ (r & 7)) * 8;
                bh[kk][nt] = *(const short8*)&Bhc[r * 64 + pos];
                bl[kk][nt] = *(const short8*)&Blc[r * 64 + pos];
            }
        }
        #pragma unroll
        for (int kk = 0; kk < 2; ++kk)
            #pragma unroll
            for (int mt = 0; mt < 4; ++mt)
                #pragma unroll
                for (int nt = 0; nt < 4; ++nt)
                    acc[mt][nt] = __builtin_amdgcn_mfma_f32_16x16x32_bf16(ah[kk][mt], bh[kk][nt], acc[mt][nt], 0, 0, 0);
        #pragma unroll
        for (int kk = 0; kk < 2; ++kk)
            #pragma unroll
            for (int mt = 0; mt < 4; ++mt)
                #pragma unroll
                for (int nt = 0; nt < 4; ++nt)
                    acc[mt][nt] = __builtin_amdgcn_mfma_f32_16x16x32_bf16(ah[kk][mt], bl[kk][nt], acc[mt][nt], 0, 0, 0);
        #pragma unroll
        for (int kk = 0; kk < 2; ++kk)
            #pragma unroll
            for (int mt = 0; mt < 4; ++mt)
                #pragma unroll
                for (int nt = 0; nt < 4; ++nt)
                    acc[mt][nt] = __builtin_amdgcn_mfma_f32_16x16x32_bf16(al[kk][mt], bh[kk][nt], acc[mt][nt], 0, 0, 0);
        // g: barrier #2 — A free for next writers, B(kt) free for B(kt+2) DMA
        __builtin_amdgcn_sched_barrier(0);
        asm volatile("s_waitcnt lgkmcnt(0)" ::: "memory");
        __builtin_amdgcn_sched_barrier(0);
        __builtin_amdgcn_s_barrier();
    };

    // prologue: B(0) -> buf0 [16], X(0) regs [4]
    issueB(Bh0, Bl0, 0);
    __builtin_amdgcn_sched_barrier(0);
    loadX(0);
    __builtin_amdgcn_sched_barrier(0);

    #pragma unroll 1
    for (int kt = 0; kt < 64; kt += 2) {
        step(Bh0, Bl0, Bh1, Bl1, kt);
        step(Bh1, Bl1, Bh0, Bl0, kt + 1);
    }
    asm volatile("" :: "v"(xr0.x), "v"(xr1.x), "v"(xr2.x), "v"(xr3.x));
    asm volatile("s_waitcnt vmcnt(0) lgkmcnt(0)" ::: "memory");

    // store logits (local token index)
    #pragma unroll
    for (int mt = 0; mt < 4; ++mt)
        #pragma unroll
        for (int nt = 0; nt < 4; ++nt)
            #pragma unroll
            for (int r = 0; r < 4; ++r)
                logits[(size_t)(mloc + mt * 16 + fq * 4 + r) * NE +
                       (e0q + nt * 16 + fr)] = acc[mt][nt][r];
}

// ============ Stage 2: routing from fp32 logits (verified epilogue) ============
__global__ __launch_bounds__(256)
void route(const float* __restrict__ logits, const float* __restrict__ bias,
           float* __restrict__ out, int* __restrict__ ws, int cap, int m_base)
{
    const int t = threadIdx.x, lane = t & 63, wv = t >> 6;
    const float4 bf4 = *(const float4*)(bias + lane * 4);
    const float bfa[4] = {bf4.x, bf4.y, bf4.z, bf4.w};

    #pragma unroll 1
    for (int tt = 0; tt < 8; ++tt) {
        const int local = blockIdx.x * 32 + wv * 8 + tt;
        const int n = m_base + local;
        const float4 lg = *(const float4*)&logits[(size_t)local * NE + lane * 4];
        const float lga[4] = {lg.x, lg.y, lg.z, lg.w};
        float s[4], sc[4];
        #pragma unroll
        for (int i = 0; i < 4; ++i) {
            s[i] = 1.f / (1.f + expf(-lga[i]));
            sc[i] = s[i] + bfa[i];
        }
        float a1 = fmaxf(sc[0], sc[1]), a2 = fminf(sc[0], sc[1]);
        float b1 = fmaxf(sc[2], sc[3]), b2 = fminf(sc[2], sc[3]);
        float t1 = fmaxf(a1, b1);
        float t2 = fmaxf(fminf(a1, b1), fmaxf(a2, b2));
        #pragma unroll
        for (int off = 1; off <= 4; off <<= 1) {
            float o1 = __shfl_xor(t1, off, 64);
            float o2 = __shfl_xor(t2, off, 64);
            float n1 = fmaxf(t1, o1);
            float n2 = fmaxf(fminf(t1, o1), fmaxf(t2, o2));
            t1 = n1; t2 = n2;
        }
        const float gsum = t1 + t2;
        float gsv[8];
        #pragma unroll
        for (int g = 0; g < 8; ++g) gsv[g] = __shfl(gsum, g * 8, 64);

        float minsel = 3e38f, maxuns = -3e38f;
        bool sel = false;
        const int myg = lane >> 3;
        #pragma unroll
        for (int g = 0; g < 8; ++g) {
            int cg = 0;
            #pragma unroll
            for (int g2 = 0; g2 < 8; ++g2)
                cg += (gsv[g2] > gsv[g] || (gsv[g2] == gsv[g] && g2 < g)) ? 1 : 0;
            const bool sg = (cg < 4);
            if (sg) minsel = fminf(minsel, gsv[g]); else maxuns = fmaxf(maxuns, gsv[g]);
            if (myg == g) sel = sg;
        }
        bool flag = (minsel - maxuns) < EPS_G;

        float v[4];
        #pragma unroll
        for (int i = 0; i < 4; ++i) v[i] = sel ? sc[i] : 0.f;

        int idxs[8]; float sigs[8];
        float denom = 0.f, prevv = 0.f;
        #pragma unroll
        for (int r = 0; r < 9; ++r) {
            float bv = v[0]; int bi = 0; float bs = s[0];
            #pragma unroll
            for (int i = 1; i < 4; ++i)
                if (v[i] > bv) { bv = v[i]; bi = i; bs = s[i]; }
            int bidx = (lane << 2) + bi;
            #pragma unroll
            for (int off = 1; off < 64; off <<= 1) {
                float ov = __shfl_xor(bv, off, 64);
                int  oi = __shfl_xor(bidx, off, 64);
                float os = __shfl_xor(bs, off, 64);
                if (ov > bv || (ov == bv && oi < bidx)) { bv = ov; bidx = oi; bs = os; }
            }
            if (r > 0) flag = flag || ((prevv - bv) < EPS_E);
            prevv = bv;
            if (r < 8) {
                idxs[r] = bidx; sigs[r] = bs; denom += bs;
                if ((bidx >> 2) == lane) {
                    #pragma unroll
                    for (int i = 0; i < 4; ++i)
                        if ((bidx & 3) == i) v[i] = -3e38f;
                }
            }
        }
        denom += 1e-20f;
        #pragma unroll
        for (int r = 0; r < 8; ++r)
            if (lane == r) {
                out[n * 8 + r] = (float)idxs[r];
                out[NTOK * 8 + n * 8 + r] = sigs[r] / denom * 2.5f;
            }
        if (flag && lane == 0) {
            int slot = atomicAdd(ws, 1);
            if (slot < cap) ws[16 + slot] = n;
        }
    }
}

// ============ fp64 fixup stage A: exact logits, expert-parallel ============
__global__ __launch_bounds__(256)
void fix1(const float* __restrict__ X, const float* __restrict__ W,
          const int* __restrict__ ws, double* __restrict__ fixlog, int cap)
{
    __shared__ float Xs4[4][4096];
    const int t = threadIdx.x, lane = t & 63, wv = t >> 6;
    int count = ws[0]; if (count > cap) count = cap;
    const int ngrp = (count + 3) >> 2;

    for (int task = blockIdx.x; task < ngrp * 8; task += (int)gridDim.x) {
        const int g = task >> 3, er = task & 7;
        int tok[4];
        #pragma unroll
        for (int q = 0; q < 4; ++q) {
            const int idx = g * 4 + q;
            tok[q] = ws[16 + (idx < count ? idx : g * 4)];
        }
        __syncthreads();
        #pragma unroll
        for (int q = 0; q < 4; ++q)
            for (int k = t * 4; k < 4096; k += 1024)
                *(float4*)&Xs4[q][k] = *(const float4*)(X + (size_t)tok[q] * H + k);
        __syncthreads();
        #pragma unroll 1
        for (int cc = 0; cc < 2; ++cc) {
            const int eb = er * 32 + wv * 8 + cc * 4;
            double a[4][4];
            #pragma unroll
            for (int q = 0; q < 4; ++q)
                #pragma unroll
                for (int ee = 0; ee < 4; ++ee) a[q][ee] = 0.0;
            for (int j = 0; j < 16; ++j) {
                const int kb = (lane + 64 * j) * 4;
                double xx[4][4];
                #pragma unroll
                for (int q = 0; q < 4; ++q) {
                    float4 x4 = *(const float4*)&Xs4[q][kb];
                    xx[q][0] = x4.x; xx[q][1] = x4.y; xx[q][2] = x4.z; xx[q][3] = x4.w;
                }
                #pragma unroll
                for (int ee = 0; ee < 4; ++ee) {
                    float4 w4 = *(const float4*)(W + (size_t)(eb + ee) * H + kb);
                    const double wd[4] = {w4.x, w4.y, w4.z, w4.w};
                    #pragma unroll
                    for (int q = 0; q < 4; ++q)
                        #pragma unroll
                        for (int kq = 0; kq < 4; ++kq)
                            a[q][ee] = fma(xx[q][kq], wd[kq], a[q][ee]);
                }
            }
            #pragma unroll
            for (int q = 0; q < 4; ++q)
                #pragma unroll
                for (int ee = 0; ee < 4; ++ee) {
                    double v = a[q][ee];
                    #pragma unroll
                    for (int off = 1; off < 64; off <<= 1)
                        v += __shfl_xor(v, off, 64);
                    if (lane == 0) fixlog[(size_t)(g * 4 + q) * NE + eb + ee] = v;
                }
        }
    }
}

// ============ fp64 fixup stage B: routing from exact logits ============
__global__ __launch_bounds__(256)
void fix2(const double* __restrict__ fixlog, const float* __restrict__ bias,
          float* __restrict__ out, const int* __restrict__ ws, int cap)
{
    const int t = threadIdx.x, lane = t & 63, wv = t >> 6;
    int count = ws[0]; if (count > cap) count = cap;
    const int ngrp = (count + 3) >> 2;

    for (int g = blockIdx.x; g < ngrp; g += (int)gridDim.x) {
        const int idx = g * 4 + wv;
        const int slot = (idx < count) ? idx : g * 4;
        const int n = ws[16 + slot];
        const double* L = fixlog + (size_t)(g * 4 + wv) * NE;

        double s[4], sc[4];
        #pragma unroll
        for (int ii = 0; ii < 4; ++ii) {
            const double Lv = L[lane * 4 + ii];
            s[ii] = 1.0 / (1.0 + exp(-Lv));
            sc[ii] = s[ii] + (double)bias[lane * 4 + ii];
        }
        double a1 = fmax(sc[0], sc[1]), a2 = fmin(sc[0], sc[1]);
        double b1 = fmax(sc[2], sc[3]), b2 = fmin(sc[2], sc[3]);
        double t1 = fmax(a1, b1);
        double t2 = fmax(fmin(a1, b1), fmax(a2, b2));
        #pragma unroll
        for (int off = 1; off <= 4; off <<= 1) {
            double o1 = __shfl_xor(t1, off, 64);
            double o2 = __shfl_xor(t2, off, 64);
            double n1 = fmax(t1, o1);
            double n2 = fmax(fmin(t1, o1), fmax(t2, o2));
            t1 = n1; t2 = n2;
        }
        const double gsum = t1 + t2;
        double gsv[8];
        #pragma unroll
        for (int gg = 0; gg < 8; ++gg) gsv[gg] = __shfl(gsum, gg * 8, 64);
        const int myg = lane >> 3;
        int cnt = 0;
        #pragma unroll
        for (int gg = 0; gg < 8; ++gg)
            cnt += (gsv[gg] > gsum || (gsv[gg] == gsum && gg < myg)) ? 1 : 0;
        const bool sel = (cnt < 4);

        double v[4];
        #pragma unroll
        for (int ii = 0; ii < 4; ++ii) v[ii] = sel ? sc[ii] : 0.0;

        int idxs[8]; double sigs[8];
        double denom = 0.0;
        #pragma unroll
        for (int r = 0; r < 8; ++r) {
            double bv = v[0]; int bi = 0; double bs = s[0];
            #pragma unroll
            for (int ii = 1; ii < 4; ++ii)
                if (v[ii] > bv) { bv = v[ii]; bi = ii; bs = s[ii]; }
            int bidx = (lane << 2) + bi;
            #pragma unroll
            for (int off = 1; off < 64; off <<= 1) {
                double ov = __shfl_xor(bv, off, 64);
                int oi = __shfl_xor(bidx, off, 64);
                double os = __shfl_xor(bs, off, 64);
                if (ov > bv || (ov == bv && oi < bidx)) { bv = ov; bidx = oi; bs = os; }
            }
            idxs[r] = bidx; sigs[r] = bs; denom += bs;
            if ((bidx >> 2) == lane) {
                #pragma unroll
                for (int ii = 0; ii < 4; ++ii)
                    if ((bidx & 3) == ii) v[ii] = -1.0e300;
            }
        }
        denom += 1e-20;
        #pragma unroll
        for (int r = 0; r < 8; ++r)
            if (lane == r) {
                out[n * 8 + r] = (float)idxs[r];
                out[NTOK * 8 + n * 8 + r] = (float)(sigs[r] / denom * 2.5);
            }
    }
}

// ============ mid fallback: R5 fused kernel (verified) ============
__global__ __launch_bounds__(512, 2)
void moe_fused(const float* __restrict__ X, const unsigned short* __restrict__ Whi,
               const unsigned short* __restrict__ Wlo, const float* __restrict__ bias,
               float* __restrict__ out, int* __restrict__ ws, int cap)
{
    __shared__ __align__(16) unsigned short smem[73728];
    unsigned short* xh  = smem;
    unsigned short* xl  = smem + 4096;
    unsigned short* wh0 = smem + 8192;
    unsigned short* wl0 = smem + 24576;
    unsigned short* wh1 = smem + 40960;
    unsigned short* wl1 = smem + 57344;

    const int t = threadIdx.x;
    const int lane = t & 63;
    const int wv = t >> 6;
    const int wr = wv >> 2;
    const int wc = wv & 3;
    const int m0 = blockIdx.x * 64;
    const int fr = lane & 15;
    const int fq = lane >> 4;

    f32x4 acc[2][4];
    #pragma unroll
    for (int a = 0; a < 2; ++a)
        #pragma unroll
        for (int b = 0; b < 4; ++b) acc[a][b] = (f32x4){0.f, 0.f, 0.f, 0.f};

    const int xrow = t >> 3;
    const int xch  = t & 7;
    const int xpos = xch ^ (xrow & 7);
    const float* gx = X + (size_t)(m0 + xrow) * H + xch * 8;

    const int wlr = lane >> 3;
    const int wlc = (lane & 7) ^ wlr;
    const unsigned short* gwh = Whi + (size_t)(wv * 8 + wlr) * H + wlc * 8;
    const unsigned short* gwl = Wlo + (size_t)(wv * 8 + wlr) * H + wlc * 8;

    auto issueW = [&](unsigned short* dh, unsigned short* dl, int kt) {
        const size_t k0 = (size_t)kt * 64;
        #pragma unroll
        for (int i = 0; i < 4; ++i) {
            __builtin_amdgcn_global_load_lds(
                (const __attribute__((address_space(1))) void*)(gwh + (size_t)(64 * i) * H + k0),
                (__attribute__((address_space(3))) void*)&dh[(wv * 8 + 64 * i) * 64], 16, 0, 0);
            __builtin_amdgcn_global_load_lds(
                (const __attribute__((address_space(1))) void*)(gwl + (size_t)(64 * i) * H + k0),
                (__attribute__((address_space(3))) void*)&dl[(wv * 8 + 64 * i) * 64], 16, 0, 0);
        }
    };

    auto kstep = [&](float4& xa, float4& xb, const unsigned short* bufh,
                     const unsigned short* bufl, unsigned short* nbufh,
                     unsigned short* nbufl, int ktw, int ktx) {
        const float xv[8] = {xa.x, xa.y, xa.z, xa.w, xb.x, xb.y, xb.z, xb.w};
        short8 h8, l8;
        #pragma unroll
        for (int j = 0; j < 8; ++j) {
            unsigned short h = f2bf(xv[j]);
            h8[j] = (short)h;
            l8[j] = (short)f2bf(xv[j] - bf2f(h));
        }
        *(short8*)&xh[xrow * 64 + xpos * 8] = h8;
        *(short8*)&xl[xrow * 64 + xpos * 8] = l8;
        asm volatile("s_waitcnt vmcnt(2) lgkmcnt(0)" ::: "memory");
        __builtin_amdgcn_sched_barrier(0);
        __builtin_amdgcn_s_barrier();
        short8 fAh[2][2], fAl[2][2], fBh[2][4], fBl[2][4];
        #pragma unroll
        for (int kk = 0; kk < 2; ++kk) {
            const int cc = ((kk * 4 + fq) ^ (fr & 7)) * 8;
            #pragma unroll
            for (int mt = 0; mt < 2; ++mt) {
                const int r = wr * 32 + mt * 16 + fr;
                fAh[kk][mt] = *(const short8*)&xh[r * 64 + cc];
                fAl[kk][mt] = *(const short8*)&xl[r * 64 + cc];
            }
            #pragma unroll
            for (int nt = 0; nt < 4; ++nt) {
                const int r = wc * 64 + nt * 16 + fr;
                fBh[kk][nt] = *(const short8*)&bufh[r * 64 + cc];
                fBl[kk][nt] = *(const short8*)&bufl[r * 64 + cc];
            }
        }
        asm volatile("s_waitcnt lgkmcnt(0)" ::: "memory");
        __builtin_amdgcn_sched_barrier(0);
        __builtin_amdgcn_s_barrier();
        issueW(nbufh, nbufl, ktw);
        __builtin_amdgcn_sched_barrier(0);
        xa = *(const float4*)(gx + (size_t)ktx * 64);
        xb = *(const float4*)(gx + (size_t)ktx * 64 + 4);
        __builtin_amdgcn_sched_barrier(0);
        __builtin_amdgcn_s_setprio(1);
        #pragma unroll
        for (int kk = 0; kk < 2; ++kk)
            #pragma unroll
            for (int mt = 0; mt < 2; ++mt)
                #pragma unroll
                for (int nt = 0; nt < 4; ++nt) {
                    acc[mt][nt] = __builtin_amdgcn_mfma_f32_16x16x32_bf16(fAh[kk][mt], fBh[kk][nt], acc[mt][nt], 0, 0, 0);
                    acc[mt][nt] = __builtin_amdgcn_mfma_f32_16x16x32_bf16(fAh[kk][mt], fBl[kk][nt], acc[mt][nt], 0, 0, 0);
                    acc[mt][nt] = __builtin_amdgcn_mfma_f32_16x16x32_bf16(fAl[kk][mt], fBh[kk][nt], acc[mt][nt], 0, 0, 0);
                }
        __builtin_amdgcn_s_setprio(0);
    };

    issueW(wh0, wl0, 0);
    __builtin_amdgcn_sched_barrier(0);
    float4 x0a = *(const float4*)(gx);
    float4 x0b = *(const float4*)(gx + 4);
    float4 x1a = *(const float4*)(gx + 64);
    float4 x1b = *(const float4*)(gx + 64 + 4);

    for (int kt = 0; kt < 64; kt += 2) {
        const int k1 = kt + 1;
        const int k2 = (kt + 2 < 64) ? kt + 2 : 0;
        const int k3 = (kt + 3 < 64) ? kt + 3 : 0;
        kstep(x0a, x0b, wh0, wl0, wh1, wl1, (k1 < 64) ? k1 : 0, k2);
        kstep(x1a, x1b, wh1, wl1, wh0, wl0, k2, k3);
    }
    asm volatile("" :: "v"(x0a.x), "v"(x0b.x), "v"(x1a.x), "v"(x1b.x));
    asm volatile("s_waitcnt vmcnt(0) lgkmcnt(0)" ::: "memory");
    __builtin_amdgcn_sched_barrier(0);
    __builtin_amdgcn_s_barrier();

    float* Ls = (float*)(smem + 8192);
    #pragma unroll
    for (int mt = 0; mt < 2; ++mt)
        #pragma unroll
        for (int nt = 0; nt < 4; ++nt)
            #pragma unroll
            for (int r = 0; r < 4; ++r)
                Ls[(wr * 32 + mt * 16 + fq * 4 + r) * 260 + (wc * 64 + nt * 16 + fr)] = acc[mt][nt][r];
    __syncthreads();

    const float4 bf4 = *(const float4*)(bias + lane * 4);
    const float bfa[4] = {bf4.x, bf4.y, bf4.z, bf4.w};

    #pragma unroll 1
    for (int tt = 0; tt < 8; ++tt) {
        const int tok = wv * 8 + tt;
        const float4 lg = *(const float4*)&Ls[tok * 260 + lane * 4];
        const float lga[4] = {lg.x, lg.y, lg.z, lg.w};
        float s[4], sc[4];
        #pragma unroll
        for (int i = 0; i < 4; ++i) {
            s[i] = 1.f / (1.f + expf(-lga[i]));
            sc[i] = s[i] + bfa[i];
        }
        float a1 = fmaxf(sc[0], sc[1]), a2 = fminf(sc[0], sc[1]);
        float b1 = fmaxf(sc[2], sc[3]), b2 = fminf(sc[2], sc[3]);
        float t1 = fmaxf(a1, b1);
        float t2 = fmaxf(fminf(a1, b1), fmaxf(a2, b2));
        #pragma unroll
        for (int off = 1; off <= 4; off <<= 1) {
            float o1 = __shfl_xor(t1, off, 64);
            float o2 = __shfl_xor(t2, off, 64);
            float n1 = fmaxf(t1, o1);
            float n2 = fmaxf(fminf(t1, o1), fmaxf(t2, o2));
            t1 = n1; t2 = n2;
        }
        const float gsum = t1 + t2;
        float gsv[8];
        #pragma unroll
        for (int g = 0; g < 8; ++g) gsv[g] = __shfl(gsum, g * 8, 64);

        float minsel = 3e38f, maxuns = -3e38f;
        bool sel = false;
        const int myg = lane >> 3;
        #pragma unroll
        for (int g = 0; g < 8; ++g) {
            int cg = 0;
            #pragma unroll
            for (int g2 = 0; g2 < 8; ++g2)
                cg += (gsv[g2] > gsv[g] || (gsv[g2] == gsv[g] && g2 < g)) ? 1 : 0;
            const bool sg = (cg < 4);
            if (sg) minsel = fminf(minsel, gsv[g]); else maxuns = fmaxf(maxuns, gsv[g]);
            if (myg == g) sel = sg;
        }
        bool flag = (minsel - maxuns) < EPS_G;

        float v[4];
        #pragma unroll
        for (int i = 0; i < 4; ++i) v[i] = sel ? sc[i] : 0.f;

        int idxs[8]; float sigs[8];
        float denom = 0.f, prevv = 0.f;
        #pragma unroll
        for (int r = 0; r < 9; ++r) {
            float bv = v[0]; int bi = 0; float bs = s[0];
            #pragma unroll
            for (int i = 1; i < 4; ++i)
                if (v[i] > bv) { bv = v[i]; bi = i; bs = s[i]; }
            int bidx = (lane << 2) + bi;
            #pragma unroll
            for (int off = 1; off < 64; off <<= 1) {
                float ov = __shfl_xor(bv, off, 64);
                int  oi = __shfl_xor(bidx, off, 64);
                float os = __shfl_xor(bs, off, 64);
                if (ov > bv || (ov == bv && oi < bidx)) { bv = ov; bidx = oi; bs = os; }
            }
            if (r > 0) flag = flag || ((prevv - bv) < EPS_E);
            prevv = bv;
            if (r < 8) {
                idxs[r] = bidx; sigs[r] = bs; denom += bs;
                if ((bidx >> 2) == lane) {
                    #pragma unroll
                    for (int i = 0; i < 4; ++i)
                        if ((bidx & 3) == i) v[i] = -3e38f;
                }
            }
        }
        denom += 1e-20f;
        const int n = m0 + tok;
        #pragma unroll
        for (int r = 0; r < 8; ++r)
            if (lane == r) {
                out[n * 8 + r] = (float)idxs[r];
                out[NTOK * 8 + n * 8 + r] = sigs[r] / denom * 2.5f;
            }
        if (flag && lane == 0) {
            int slot = atomicAdd(ws, 1);
            if (slot < cap) ws[16 + slot] = n;
        }
    }
}

// old 1-token fixup (for fused fallback path)
__global__ __launch_bounds__(256)
void moe_fix(const float* __restrict__ X, const float* __restrict__ W,
             const float* __restrict__ bias, float* __restrict__ out,
             const int* __restrict__ ws, int cap)
{
    __shared__ double Xd[H];
    __shared__ double Ld[NE];
    const int t = threadIdx.x;
    const int lane = t & 63;
    const int wv = t >> 6;
    int count = ws[0]; if (count > cap) count = cap;

    for (int i = blockIdx.x; i < count; i += (int)gridDim.x) {
        const int n = ws[16 + i];
        __syncthreads();
        const float* xrow = X + (size_t)n * H;
        for (int k = t * 4; k < H; k += 1024) {
            float4 x4 = *(const float4*)(xrow + k);
            Xd[k] = (double)x4.x; Xd[k + 1] = (double)x4.y;
            Xd[k + 2] = (double)x4.z; Xd[k + 3] = (double)x4.w;
        }
        __syncthreads();
        #pragma unroll 1
        for (int cc = 0; cc < 16; ++cc) {
            const int e0 = wv * 64 + cc * 4;
            double a[4] = {0.0, 0.0, 0.0, 0.0};
            for (int j = 0; j < 16; ++j) {
                const int kb = (lane + 64 * j) * 4;
                const double x0 = Xd[kb], x1 = Xd[kb + 1], x2 = Xd[kb + 2], x3 = Xd[kb + 3];
                #pragma unroll
                for (int ee = 0; ee < 4; ++ee) {
                    float4 w4 = *(const float4*)(W + (size_t)(e0 + ee) * H + kb);
                    a[ee] = fma(x0, (double)w4.x, a[ee]);
                    a[ee] = fma(x1, (double)w4.y, a[ee]);
                    a[ee] = fma(x2, (double)w4.z, a[ee]);
                    a[ee] = fma(x3, (double)w4.w, a[ee]);
                }
            }
            #pragma unroll
            for (int ee = 0; ee < 4; ++ee)
                #pragma unroll
                for (int off = 1; off < 64; off <<= 1)
                    a[ee] += __shfl_xor(a[ee], off, 64);
            if (lane == 0) { Ld[e0] = a[0]; Ld[e0 + 1] = a[1]; Ld[e0 + 2] = a[2]; Ld[e0 + 3] = a[3]; }
        }
        __syncthreads();
        if (wv == 0) {
            double s[4], sc[4];
            #pragma unroll
            for (int ii = 0; ii < 4; ++ii) {
                const double L = Ld[lane * 4 + ii];
                s[ii] = 1.0 / (1.0 + exp(-L));
                sc[ii] = s[ii] + (double)bias[lane * 4 + ii];
            }
            double a1 = fmax(sc[0], sc[1]), a2 = fmin(sc[0], sc[1]);
            double b1 = fmax(sc[2], sc[3]), b2 = fmin(sc[2], sc[3]);
            double t1 = fmax(a1, b1);
            double t2 = fmax(fmin(a1, b1), fmax(a2, b2));
            #pragma unroll
            for (int off = 1; off <= 4; off <<= 1) {
                double o1 = __shfl_xor(t1, off, 64);
                double o2 = __shfl_xor(t2, off, 64);
                double n1 = fmax(t1, o1);
                double n2 = fmax(fmin(t1, o1), fmax(t2, o2));
                t1 = n1; t2 = n2;
            }
            const double gsum = t1 + t2;
            double gsv[8];
            #pragma unroll
            for (int g = 0; g < 8; ++g) gsv[g] = __shfl(gsum, g * 8, 64);
            const int myg = lane >> 3;
            int cnt = 0;
            #pragma unroll
            for (int g = 0; g < 8; ++g)
                cnt += (gsv[g] > gsum || (gsv[g] == gsum && g < myg)) ? 1 : 0;
            const bool sel = (cnt < 4);
            double v[4];
            #pragma unroll
            for (int ii = 0; ii < 4; ++ii) v[ii] = sel ? sc[ii] : 0.0;
            int idxs[8]; double sigs[8];
            double denom = 0.0;
            #pragma unroll
            for (int r = 0; r < 8; ++r) {
                double bv = v[0]; int bi = 0; double bs = s[0];
                #pragma unroll
                for (int ii = 1; ii < 4; ++ii)
                    if (v[ii] > bv) { bv = v[ii]; bi = ii; bs = s[ii]; }
                int bidx = (lane << 2) + bi;
                #pragma unroll
                for (int off = 1; off < 64; off <<= 1) {
                    double ov = __shfl_xor(bv, off, 64);
                    int oi = __shfl_xor(bidx, off, 64);
                    double os = __shfl_xor(bs, off, 64);
                    if (ov > bv || (ov == bv && oi < bidx)) { bv = ov; bidx = oi; bs = os; }
                }
                idxs[r] = bidx; sigs[r] = bs; denom += bs;
                if ((bidx >> 2) == lane) {
                    #pragma unroll
                    for (int ii = 0; ii < 4; ++ii)
                        if ((bidx & 3) == ii) v[ii] = -1.0e300;
                }
            }
            denom += 1e-20;
            #pragma unroll
            for (int r = 0; r < 8; ++r)
                if (lane == r) {
                    out[n * 8 + r] = (float)idxs[r];
                    out[NTOK * 8 + n * 8 + r] = (float)(sigs[r] / denom * 2.5);
                }
        }
    }
}

// low fallback: exact fp64 (slow but correct)
#define FXP 34
#define FEP 260
__global__ __launch_bounds__(256)
void moe_fb(const float* __restrict__ X, const float* __restrict__ W,
            const float* __restrict__ bias, float* __restrict__ out)
{
    __shared__ double Xs[16 * FXP];
    __shared__ double Ws[16 * FEP];
    const int t = threadIdx.x;
    const int lane = t & 63;
    const int wv = t >> 6;
    const int m0 = blockIdx.x * 32;
    double acc[8][4];
    #pragma unroll
    for (int i = 0; i < 8; ++i)
        #pragma unroll
        for (int j = 0; j < 4; ++j) acc[i][j] = 0.0;
    const int xm = t >> 3, xk = (t & 7) * 2;
    const int we = t >> 2, wk = (t & 3) * 4;
    const float* gx = X + (size_t)(m0 + xm) * H + xk;
    const float* gw = W + (size_t)we * H + wk;
    float2 xreg = *(const float2*)(gx);
    float4 wreg[4];
    #pragma unroll
    for (int p = 0; p < 4; ++p) wreg[p] = *(const float4*)(gw + (size_t)(64 * p) * H);
    const int NT = H / 16;
    for (int t0 = 0; t0 < NT; ++t0) {
        __syncthreads();
        Xs[(xk + 0) * FXP + xm] = (double)xreg.x;
        Xs[(xk + 1) * FXP + xm] = (double)xreg.y;
        #pragma unroll
        for (int p = 0; p < 4; ++p) {
            const int e = we + 64 * p;
            Ws[(wk + 0) * FEP + e] = (double)wreg[p].x;
            Ws[(wk + 1) * FEP + e] = (double)wreg[p].y;
            Ws[(wk + 2) * FEP + e] = (double)wreg[p].z;
            Ws[(wk + 3) * FEP + e] = (double)wreg[p].w;
        }
        __syncthreads();
        if (t0 + 1 < NT) {
            const int off = (t0 + 1) * 16;
            xreg = *(const float2*)(gx + off);
            #pragma unroll
            for (int p = 0; p < 4; ++p) wreg[p] = *(const float4*)(gw + (size_t)(64 * p) * H + off);
        }
        #pragma unroll
        for (int j = 0; j < 16; ++j) {
            const double* xrow = &Xs[j * FXP + wv * 8];
            const double2 wa = *(const double2*)&Ws[j * FEP + lane * 4];
            const double2 wb = *(const double2*)&Ws[j * FEP + lane * 4 + 2];
            const double ws4[4] = {wa.x, wa.y, wb.x, wb.y};
            #pragma unroll
            for (int mi = 0; mi < 8; ++mi)
                #pragma unroll
                for (int ei = 0; ei < 4; ++ei)
                    acc[mi][ei] = fma(xrow[mi], ws4[ei], acc[mi][ei]);
        }
    }
    const float4 bf = *(const float4*)(bias + lane * 4);
    const double bfa[4] = {(double)bf.x, (double)bf.y, (double)bf.z, (double)bf.w};
    #pragma unroll 1
    for (int tt = 0; tt < 8; ++tt) {
        double s[4], sc[4];
        #pragma unroll
        for (int i = 0; i < 4; ++i) {
            s[i] = 1.0 / (1.0 + exp(-acc[tt][i]));
            sc[i] = s[i] + bfa[i];
        }
        double a1 = fmax(sc[0], sc[1]), a2 = fmin(sc[0], sc[1]);
        double b1 = fmax(sc[2], sc[3]), b2 = fmin(sc[2], sc[3]);
        double t1 = fmax(a1, b1);
        double t2 = fmax(fmin(a1, b1), fmax(a2, b2));
        #pragma unroll
        for (int off = 1; off <= 4; off <<= 1) {
            double o1 = __shfl_xor(t1, off, 64);
            double o2 = __shfl_xor(t2, off, 64);
            double n1 = fmax(t1, o1);
            double n2 = fmax(fmin(t1, o1), fmax(t2, o2));
            t1 = n1; t2 = n2;
        }
        const double gsum = t1 + t2;
        double gsv[8];
        #pragma unroll
        for (int g = 0; g < 8; ++g) gsv[g] = __shfl(gsum, g * 8, 64);
        const int myg = lane >> 3;
        int cnt = 0;
        #pragma unroll
        for (int g = 0; g < 8; ++g)
            cnt += (gsv[g] > gsum || (gsv[g] == gsum && g < myg)) ? 1 : 0;
        const bool sel = (cnt < 4);
        double v[4];
        #pragma unroll
        for (int i = 0; i < 4; ++i) v[i] = sel ? sc[i] : 0.0;
        int idxs[8]; double sigs[8];
        double denom = 0.0;
        #pragma unroll
        for (int r = 0; r < 8; ++r) {
            double bv = v[0]; int bi = 0; double bs = s[0];
            #pragma unroll
            for (int i = 1; i < 4; ++i)
                if (v[i] > bv) { bv = v[i]; bi = i; bs = s[i]; }
            int bidx = (lane << 2) + bi;
            #pragma unroll
            for (int off = 1; off < 64; off <<= 1) {
                double ov = __shfl_xor(bv, off, 64);
                int oi = __shfl_xor(bidx, off, 64);
                double os = __shfl_xor(bs, off, 64);
                if (ov > bv || (ov == bv && oi < bidx)) { bv = ov; bidx = oi; bs = os; }
            }
            idxs[r] = bidx; sigs[r] = bs; denom += bs;
            if ((bidx >> 2) == lane) {
                #pragma unroll
                for (int i = 0; i < 4; ++i)
                    if ((bidx & 3) == i) v[i] = -1.0e300;
            }
        }
        denom += 1e-20;
        const size_t n = (size_t)(m0 + wv * 8 + tt);
        #pragma unroll
        for (int r = 0; r < 8; ++r)
            if (lane == r) {
                out[n * 8 + r] = (float)idxs[r];
                out[(size_t)NTOK * 8 + n * 8 + r] = (float)(sigs[r] / denom * 2.5);
            }
    }
}

extern "C" void kernel_launch(void* const* d_in, const int* in_sizes, int n_in,
                              void* d_out, int out_size, void* d_ws, size_t ws_size,
                              hipStream_t stream) {
    const float* X = (const float*)d_in[0];
    const float* W = (const float*)d_in[1];
    const float* bias = (const float*)d_in[2];
    float* out = (float*)d_out;

    const size_t WB = (size_t)NE * H * 2;
    const size_t OFF_W = 65536;
    const size_t OFF_FIX = OFF_W + 2 * WB;
    const size_t FIXB = (size_t)FIXCAP * NE * 8;
    const size_t OFF_LOG = OFF_FIX + FIXB;
    const size_t NEED1 = OFF_FIX;
    const size_t minlog = (size_t)256 * NE * 4;

    if (ws_size < NEED1) {
        moe_fb<<<NTOK / 32, 256, 0, stream>>>(X, W, bias, out);
        return;
    }
    int* ws = (int*)d_ws;
    unsigned short* whi = (unsigned short*)((char*)d_ws + OFF_W);
    unsigned short* wlo = whi + (size_t)NE * H;

    zero_ws<<<1, 64, 0, stream>>>(ws);
    split_w<<<(NE * H) / 1024, 256, 0, stream>>>(W, whi, wlo);

    if (ws_size >= OFF_LOG + minlog) {
        double* fixlog = (double*)((char*)d_ws + OFF_FIX);
        float* logits = (float*)((char*)d_ws + OFF_LOG);
        const size_t avail = ws_size - OFF_LOG;
        size_t full = (size_t)NTOK * NE * 4;
        int CT;
        if (avail >= full) CT = NTOK;
        else {
            CT = (int)(avail / ((size_t)NE * 4));
            CT &= ~255;
        }
        for (int mb0 = 0; mb0 < NTOK; mb0 += CT) {
            int ct = (NTOK - mb0 < CT) ? (NTOK - mb0) : CT;
            gemm3<<<ct / 64, 256, 0, stream>>>(X, whi, wlo, logits, mb0);
            route<<<ct / 32, 256, 0, stream>>>(logits, bias, out, ws, FLAGCAP, mb0);
        }
        fix1<<<2048, 256, 0, stream>>>(X, W, ws, fixlog, FIXCAP);
        fix2<<<256, 256, 0, stream>>>(fixlog, bias, out, ws, FIXCAP);
    } else {
        moe_fused<<<NTOK / 64, 512, 0, stream>>>(X, whi, wlo, bias, out, ws, FLAGCAP);
        moe_fix<<<1024, 256, 0, stream>>>(X, W, bias, out, ws, FLAGCAP);
    }
}

// Round 13
// 256.838 us; speedup vs baseline: 1.0082x; 1.0082x over previous
//
#include <hip/hip_runtime.h>
#include <math.h>

#define NTOK 16384
#define H 4096
#define NE 256
#define EPS_E 1.2e-5f
#define EPS_G 2.4e-5f
#define FIXCAP 1024
#define FLAGCAP 8192

typedef __attribute__((ext_vector_type(8))) short short8;
typedef __attribute__((ext_vector_type(4))) float f32x4;

__device__ __forceinline__ unsigned short f2bf(float x) {
    union { float f; unsigned u; } v; v.f = x;
    unsigned r = v.u + 0x7FFF + ((v.u >> 16) & 1);
    return (unsigned short)(r >> 16);
}
__device__ __forceinline__ float bf2f(unsigned short h) {
    union { float f; unsigned u; } v; v.u = ((unsigned)h) << 16;
    return v.f;
}

__global__ void zero_ws(int* ws) { if (threadIdx.x == 0) ws[0] = 0; }

__global__ __launch_bounds__(256)
void split_w(const float* __restrict__ W, unsigned short* __restrict__ whi,
             unsigned short* __restrict__ wlo)
{
    const int i = (blockIdx.x * 256 + threadIdx.x) * 4;
    float4 w4 = *(const float4*)(W + i);
    const float wv[4] = {w4.x, w4.y, w4.z, w4.w};
    ushort4 hh, ll;
    unsigned short* hp = (unsigned short*)&hh;
    unsigned short* lp = (unsigned short*)&ll;
    #pragma unroll
    for (int j = 0; j < 4; ++j) {
        unsigned short h = f2bf(wv[j]);
        hp[j] = h;
        lp[j] = f2bf(wv[j] - bf2f(h));
    }
    *(ushort4*)(whi + i) = hh;
    *(ushort4*)(wlo + i) = ll;
}

// ============ Stage 1: BM=32 x BN=128, 4 waves, 40KB LDS, 4 blocks/CU ============
__global__ __launch_bounds__(256, 4)
void gemm3(const float* __restrict__ X, const unsigned short* __restrict__ Whi,
           const unsigned short* __restrict__ Wlo, float* __restrict__ logits,
           int m_base)
{
    __shared__ __align__(16) unsigned short smem[20480];  // 40 KB
    unsigned short* Bh = smem;              // [128][64] 16KB
    unsigned short* Bl = smem + 8192;       // 16KB
    unsigned short* Ah = smem + 16384;      // [32][64] 4KB, XOR-swizzled
    unsigned short* Al = smem + 18432;      // 4KB

    const int t = threadIdx.x;
    const int lane = t & 63;
    const int w = t >> 6;                   // wave 0..3 -> 32-expert slice
    const int fr = lane & 15, fq = lane >> 4;

    const int G = (int)gridDim.x;
    const int swz = (blockIdx.x & 7) * (G >> 3) + (blockIdx.x >> 3);
    const int nb = swz & 1;
    const int mb = swz >> 1;
    const int mloc = mb * 32;
    const int m0 = m_base + mloc;
    const int e0 = nb * 128;

    f32x4 acc[2][2];
    #pragma unroll
    for (int a = 0; a < 2; ++a)
        #pragma unroll
        for (int b = 0; b < 2; ++b) acc[a][b] = (f32x4){0.f, 0.f, 0.f, 0.f};

    // A staging (R5-fused proven map): thread t -> row t>>3 (0..31), chunk t&7
    const int ar = t >> 3;
    const int ac = t & 7;
    const int apos = (ac ^ (ar & 7)) * 8;
    const float* gxa = X + (size_t)(m0 + ar) * H + ac * 8;

    // B staging (R11 verbatim): linear dest, pre-swizzled source
    const int blr = lane >> 3;
    const int bsrc = (lane & 7) ^ blr;
    const unsigned short* gbh = Whi + (size_t)(e0 + w * 8 + blr) * H + bsrc * 8;
    const unsigned short* gbl = Wlo + (size_t)(e0 + w * 8 + blr) * H + bsrc * 8;

    auto issueB = [&](int kt) {
        const size_t k0 = (size_t)kt * 64;
        #pragma unroll
        for (int i = 0; i < 4; ++i) {
            __builtin_amdgcn_global_load_lds(
                (const __attribute__((address_space(1))) void*)(gbh + (size_t)(32 * i) * H + k0),
                (__attribute__((address_space(3))) void*)&Bh[(w * 8 + 32 * i) * 64], 16, 0, 0);
            __builtin_amdgcn_global_load_lds(
                (const __attribute__((address_space(1))) void*)(gbl + (size_t)(32 * i) * H + k0),
                (__attribute__((address_space(3))) void*)&Bl[(w * 8 + 32 * i) * 64], 16, 0, 0);
        }
    };

    float4 xr0, xr1;
    auto loadX = [&](int kt) {
        const float* p = gxa + (size_t)kt * 64;
        xr0 = *(const float4*)p;
        xr1 = *(const float4*)(p + 4);
    };

    // prologue: X(0) in regs [2 outstanding]
    loadX(0);
    __builtin_amdgcn_sched_barrier(0);

    #pragma unroll 1
    for (int kt = 0; kt < 64; ++kt) {
        // a: issue B(kt) [+8/wave] -> outstanding: 8 B + 2 X(kt) (X older)
        issueB(kt);
        __builtin_amdgcn_sched_barrier(0);
        // b: X(kt) landed (keep the 8 B in flight)
        asm volatile("s_waitcnt vmcnt(8)" ::: "memory");
        __builtin_amdgcn_sched_barrier(0);
        // c: split X(kt) -> swizzled A LDS write (8 el/thread)
        {
            const float xf[8] = {xr0.x, xr0.y, xr0.z, xr0.w, xr1.x, xr1.y, xr1.z, xr1.w};
            short8 h8, l8;
            #pragma unroll
            for (int j = 0; j < 8; ++j) {
                union { float f; unsigned u; } uu; uu.f = xf[j];
                union { unsigned u; float f; } hh; hh.u = uu.u & 0xFFFF0000u;
                union { float f; unsigned u; } ll; ll.f = xf[j] - hh.f;
                h8[j] = (short)(uu.u >> 16);
                l8[j] = (short)(ll.u >> 16);
            }
            *(short8*)&Ah[ar * 64 + apos] = h8;
            *(short8*)&Al[ar * 64 + apos] = l8;
        }
        // d: prefetch X(kt+1) [+2 -> 10 outstanding]
        loadX(kt + 1 < 64 ? kt + 1 : 63);
        __builtin_amdgcn_sched_barrier(0);
        // e: B(kt) landed (keep X(kt+1) 2 in flight); A writes visible -> barrier #1
        asm volatile("s_waitcnt vmcnt(2) lgkmcnt(0)" ::: "memory");
        __builtin_amdgcn_sched_barrier(0);
        __builtin_amdgcn_s_barrier();
        // f: per-kk frag reads + 12 MFMA (compiler interleaves via counted lgkmcnt)
        #pragma unroll
        for (int kk = 0; kk < 2; ++kk) {
            short8 ah[2], al[2], bh[2], bl[2];
            #pragma unroll
            for (int mt = 0; mt < 2; ++mt) {
                const int r = mt * 16 + fr;
                const int pos = ((kk * 4 + fq) ^ (r & 7)) * 8;
                ah[mt] = *(const short8*)&Ah[r * 64 + pos];
                al[mt] = *(const short8*)&Al[r * 64 + pos];
            }
            #pragma unroll
            for (int nt = 0; nt < 2; ++nt) {
                const int r = w * 32 + nt * 16 + fr;
                const int pos = ((kk * 4 + fq) ^ (r & 7)) * 8;
                bh[nt] = *(const short8*)&Bh[r * 64 + pos];
                bl[nt] = *(const short8*)&Bl[r * 64 + pos];
            }
            #pragma unroll
            for (int mt = 0; mt < 2; ++mt)
                #pragma unroll
                for (int nt = 0; nt < 2; ++nt)
                    acc[mt][nt] = __builtin_amdgcn_mfma_f32_16x16x32_bf16(ah[mt], bh[nt], acc[mt][nt], 0, 0, 0);
            #pragma unroll
            for (int mt = 0; mt < 2; ++mt)
                #pragma unroll
                for (int nt = 0; nt < 2; ++nt)
                    acc[mt][nt] = __builtin_amdgcn_mfma_f32_16x16x32_bf16(ah[mt], bl[nt], acc[mt][nt], 0, 0, 0);
            #pragma unroll
            for (int mt = 0; mt < 2; ++mt)
                #pragma unroll
                for (int nt = 0; nt < 2; ++nt)
                    acc[mt][nt] = __builtin_amdgcn_mfma_f32_16x16x32_bf16(al[mt], bh[nt], acc[mt][nt], 0, 0, 0);
        }
        // g: all reads done -> release A and B buffers for next step's writers
        __builtin_amdgcn_sched_barrier(0);
        asm volatile("s_waitcnt lgkmcnt(0)" ::: "memory");
        __builtin_amdgcn_sched_barrier(0);
        __builtin_amdgcn_s_barrier();
    }
    asm volatile("" :: "v"(xr0.x), "v"(xr0.y), "v"(xr0.z), "v"(xr0.w),
                       "v"(xr1.x), "v"(xr1.y), "v"(xr1.z), "v"(xr1.w));
    asm volatile("s_waitcnt vmcnt(0) lgkmcnt(0)" ::: "memory");

    // store logits (local token index)
    #pragma unroll
    for (int mt = 0; mt < 2; ++mt)
        #pragma unroll
        for (int nt = 0; nt < 2; ++nt)
            #pragma unroll
            for (int r = 0; r < 4; ++r)
                logits[(size_t)(mloc + mt * 16 + fq * 4 + r) * NE +
                       (e0 + w * 32 + nt * 16 + fr)] = acc[mt][nt][r];
}

// ============ Stage 2: routing from fp32 logits (verified epilogue) ============
__global__ __launch_bounds__(256)
void route(const float* __restrict__ logits, const float* __restrict__ bias,
           float* __restrict__ out, int* __restrict__ ws, int cap, int m_base)
{
    const int t = threadIdx.x, lane = t & 63, wv = t >> 6;
    const float4 bf4 = *(const float4*)(bias + lane * 4);
    const float bfa[4] = {bf4.x, bf4.y, bf4.z, bf4.w};

    #pragma unroll 1
    for (int tt = 0; tt < 8; ++tt) {
        const int local = blockIdx.x * 32 + wv * 8 + tt;
        const int n = m_base + local;
        const float4 lg = *(const float4*)&logits[(size_t)local * NE + lane * 4];
        const float lga[4] = {lg.x, lg.y, lg.z, lg.w};
        float s[4], sc[4];
        #pragma unroll
        for (int i = 0; i < 4; ++i) {
            s[i] = 1.f / (1.f + expf(-lga[i]));
            sc[i] = s[i] + bfa[i];
        }
        float a1 = fmaxf(sc[0], sc[1]), a2 = fminf(sc[0], sc[1]);
        float b1 = fmaxf(sc[2], sc[3]), b2 = fminf(sc[2], sc[3]);
        float t1 = fmaxf(a1, b1);
        float t2 = fmaxf(fminf(a1, b1), fmaxf(a2, b2));
        #pragma unroll
        for (int off = 1; off <= 4; off <<= 1) {
            float o1 = __shfl_xor(t1, off, 64);
            float o2 = __shfl_xor(t2, off, 64);
            float n1 = fmaxf(t1, o1);
            float n2 = fmaxf(fminf(t1, o1), fmaxf(t2, o2));
            t1 = n1; t2 = n2;
        }
        const float gsum = t1 + t2;
        float gsv[8];
        #pragma unroll
        for (int g = 0; g < 8; ++g) gsv[g] = __shfl(gsum, g * 8, 64);

        float minsel = 3e38f, maxuns = -3e38f;
        bool sel = false;
        const int myg = lane >> 3;
        #pragma unroll
        for (int g = 0; g < 8; ++g) {
            int cg = 0;
            #pragma unroll
            for (int g2 = 0; g2 < 8; ++g2)
                cg += (gsv[g2] > gsv[g] || (gsv[g2] == gsv[g] && g2 < g)) ? 1 : 0;
            const bool sg = (cg < 4);
            if (sg) minsel = fminf(minsel, gsv[g]); else maxuns = fmaxf(maxuns, gsv[g]);
            if (myg == g) sel = sg;
        }
        bool flag = (minsel - maxuns) < EPS_G;

        float v[4];
        #pragma unroll
        for (int i = 0; i < 4; ++i) v[i] = sel ? sc[i] : 0.f;

        int idxs[8]; float sigs[8];
        float denom = 0.f, prevv = 0.f;
        #pragma unroll
        for (int r = 0; r < 9; ++r) {
            float bv = v[0]; int bi = 0; float bs = s[0];
            #pragma unroll
            for (int i = 1; i < 4; ++i)
                if (v[i] > bv) { bv = v[i]; bi = i; bs = s[i]; }
            int bidx = (lane << 2) + bi;
            #pragma unroll
            for (int off = 1; off < 64; off <<= 1) {
                float ov = __shfl_xor(bv, off, 64);
                int  oi = __shfl_xor(bidx, off, 64);
                float os = __shfl_xor(bs, off, 64);
                if (ov > bv || (ov == bv && oi < bidx)) { bv = ov; bidx = oi; bs = os; }
            }
            if (r > 0) flag = flag || ((prevv - bv) < EPS_E);
            prevv = bv;
            if (r < 8) {
                idxs[r] = bidx; sigs[r] = bs; denom += bs;
                if ((bidx >> 2) == lane) {
                    #pragma unroll
                    for (int i = 0; i < 4; ++i)
                        if ((bidx & 3) == i) v[i] = -3e38f;
                }
            }
        }
        denom += 1e-20f;
        #pragma unroll
        for (int r = 0; r < 8; ++r)
            if (lane == r) {
                out[n * 8 + r] = (float)idxs[r];
                out[NTOK * 8 + n * 8 + r] = sigs[r] / denom * 2.5f;
            }
        if (flag && lane == 0) {
            int slot = atomicAdd(ws, 1);
            if (slot < cap) ws[16 + slot] = n;
        }
    }
}

// ============ fp64 fixup stage A: exact logits, expert-parallel ============
__global__ __launch_bounds__(256)
void fix1(const float* __restrict__ X, const float* __restrict__ W,
          const int* __restrict__ ws, double* __restrict__ fixlog, int cap)
{
    __shared__ float Xs4[4][4096];
    const int t = threadIdx.x, lane = t & 63, wv = t >> 6;
    int count = ws[0]; if (count > cap) count = cap;
    const int ngrp = (count + 3) >> 2;

    for (int task = blockIdx.x; task < ngrp * 8; task += (int)gridDim.x) {
        const int g = task >> 3, er = task & 7;
        int tok[4];
        #pragma unroll
        for (int q = 0; q < 4; ++q) {
            const int idx = g * 4 + q;
            tok[q] = ws[16 + (idx < count ? idx : g * 4)];
        }
        __syncthreads();
        #pragma unroll
        for (int q = 0; q < 4; ++q)
            for (int k = t * 4; k < 4096; k += 1024)
                *(float4*)&Xs4[q][k] = *(const float4*)(X + (size_t)tok[q] * H + k);
        __syncthreads();
        #pragma unroll 1
        for (int cc = 0; cc < 2; ++cc) {
            const int eb = er * 32 + wv * 8 + cc * 4;
            double a[4][4];
            #pragma unroll
            for (int q = 0; q < 4; ++q)
                #pragma unroll
                for (int ee = 0; ee < 4; ++ee) a[q][ee] = 0.0;
            for (int j = 0; j < 16; ++j) {
                const int kb = (lane + 64 * j) * 4;
                double xx[4][4];
                #pragma unroll
                for (int q = 0; q < 4; ++q) {
                    float4 x4 = *(const float4*)&Xs4[q][kb];
                    xx[q][0] = x4.x; xx[q][1] = x4.y; xx[q][2] = x4.z; xx[q][3] = x4.w;
                }
                #pragma unroll
                for (int ee = 0; ee < 4; ++ee) {
                    float4 w4 = *(const float4*)(W + (size_t)(eb + ee) * H + kb);
                    const double wd[4] = {w4.x, w4.y, w4.z, w4.w};
                    #pragma unroll
                    for (int q = 0; q < 4; ++q)
                        #pragma unroll
                        for (int kq = 0; kq < 4; ++kq)
                            a[q][ee] = fma(xx[q][kq], wd[kq], a[q][ee]);
                }
            }
            #pragma unroll
            for (int q = 0; q < 4; ++q)
                #pragma unroll
                for (int ee = 0; ee < 4; ++ee) {
                    double v = a[q][ee];
                    #pragma unroll
                    for (int off = 1; off < 64; off <<= 1)
                        v += __shfl_xor(v, off, 64);
                    if (lane == 0) fixlog[(size_t)(g * 4 + q) * NE + eb + ee] = v;
                }
        }
    }
}

// ============ fp64 fixup stage B: routing from exact logits ============
__global__ __launch_bounds__(256)
void fix2(const double* __restrict__ fixlog, const float* __restrict__ bias,
          float* __restrict__ out, const int* __restrict__ ws, int cap)
{
    const int t = threadIdx.x, lane = t & 63, wv = t >> 6;
    int count = ws[0]; if (count > cap) count = cap;
    const int ngrp = (count + 3) >> 2;

    for (int g = blockIdx.x; g < ngrp; g += (int)gridDim.x) {
        const int idx = g * 4 + wv;
        const int slot = (idx < count) ? idx : g * 4;
        const int n = ws[16 + slot];
        const double* L = fixlog + (size_t)(g * 4 + wv) * NE;

        double s[4], sc[4];
        #pragma unroll
        for (int ii = 0; ii < 4; ++ii) {
            const double Lv = L[lane * 4 + ii];
            s[ii] = 1.0 / (1.0 + exp(-Lv));
            sc[ii] = s[ii] + (double)bias[lane * 4 + ii];
        }
        double a1 = fmax(sc[0], sc[1]), a2 = fmin(sc[0], sc[1]);
        double b1 = fmax(sc[2], sc[3]), b2 = fmin(sc[2], sc[3]);
        double t1 = fmax(a1, b1);
        double t2 = fmax(fmin(a1, b1), fmax(a2, b2));
        #pragma unroll
        for (int off = 1; off <= 4; off <<= 1) {
            double o1 = __shfl_xor(t1, off, 64);
            double o2 = __shfl_xor(t2, off, 64);
            double n1 = fmax(t1, o1);
            double n2 = fmax(fmin(t1, o1), fmax(t2, o2));
            t1 = n1; t2 = n2;
        }
        const double gsum = t1 + t2;
        double gsv[8];
        #pragma unroll
        for (int gg = 0; gg < 8; ++gg) gsv[gg] = __shfl(gsum, gg * 8, 64);
        const int myg = lane >> 3;
        int cnt = 0;
        #pragma unroll
        for (int gg = 0; gg < 8; ++gg)
            cnt += (gsv[gg] > gsum || (gsv[gg] == gsum && gg < myg)) ? 1 : 0;
        const bool sel = (cnt < 4);

        double v[4];
        #pragma unroll
        for (int ii = 0; ii < 4; ++ii) v[ii] = sel ? sc[ii] : 0.0;

        int idxs[8]; double sigs[8];
        double denom = 0.0;
        #pragma unroll
        for (int r = 0; r < 8; ++r) {
            double bv = v[0]; int bi = 0; double bs = s[0];
            #pragma unroll
            for (int ii = 1; ii < 4; ++ii)
                if (v[ii] > bv) { bv = v[ii]; bi = ii; bs = s[ii]; }
            int bidx = (lane << 2) + bi;
            #pragma unroll
            for (int off = 1; off < 64; off <<= 1) {
                double ov = __shfl_xor(bv, off, 64);
                int oi = __shfl_xor(bidx, off, 64);
                double os = __shfl_xor(bs, off, 64);
                if (ov > bv || (ov == bv && oi < bidx)) { bv = ov; bidx = oi; bs = os; }
            }
            idxs[r] = bidx; sigs[r] = bs; denom += bs;
            if ((bidx >> 2) == lane) {
                #pragma unroll
                for (int ii = 0; ii < 4; ++ii)
                    if ((bidx & 3) == ii) v[ii] = -1.0e300;
            }
        }
        denom += 1e-20;
        #pragma unroll
        for (int r = 0; r < 8; ++r)
            if (lane == r) {
                out[n * 8 + r] = (float)idxs[r];
                out[NTOK * 8 + n * 8 + r] = (float)(sigs[r] / denom * 2.5);
            }
    }
}

// ============ mid fallback: R5 fused kernel (verified) ============
__global__ __launch_bounds__(512, 2)
void moe_fused(const float* __restrict__ X, const unsigned short* __restrict__ Whi,
               const unsigned short* __restrict__ Wlo, const float* __restrict__ bias,
               float* __restrict__ out, int* __restrict__ ws, int cap)
{
    __shared__ __align__(16) unsigned short smem[73728];
    unsigned short* xh  = smem;
    unsigned short* xl  = smem + 4096;
    unsigned short* wh0 = smem + 8192;
    unsigned short* wl0 = smem + 24576;
    unsigned short* wh1 = smem + 40960;
    unsigned short* wl1 = smem + 57344;

    const int t = threadIdx.x;
    const int lane = t & 63;
    const int wv = t >> 6;
    const int wr = wv >> 2;
    const int wc = wv & 3;
    const int m0 = blockIdx.x * 64;
    const int fr = lane & 15;
    const int fq = lane >> 4;

    f32x4 acc[2][4];
    #pragma unroll
    for (int a = 0; a < 2; ++a)
        #pragma unroll
        for (int b = 0; b < 4; ++b) acc[a][b] = (f32x4){0.f, 0.f, 0.f, 0.f};

    const int xrow = t >> 3;
    const int xch  = t & 7;
    const int xpos = xch ^ (xrow & 7);
    const float* gx = X + (size_t)(m0 + xrow) * H + xch * 8;

    const int wlr = lane >> 3;
    const int wlc = (lane & 7) ^ wlr;
    const unsigned short* gwh = Whi + (size_t)(wv * 8 + wlr) * H + wlc * 8;
    const unsigned short* gwl = Wlo + (size_t)(wv * 8 + wlr) * H + wlc * 8;

    auto issueW = [&](unsigned short* dh, unsigned short* dl, int kt) {
        const size_t k0 = (size_t)kt * 64;
        #pragma unroll
        for (int i = 0; i < 4; ++i) {
            __builtin_amdgcn_global_load_lds(
                (const __attribute__((address_space(1))) void*)(gwh + (size_t)(64 * i) * H + k0),
                (__attribute__((address_space(3))) void*)&dh[(wv * 8 + 64 * i) * 64], 16, 0, 0);
            __builtin_amdgcn_global_load_lds(
                (const __attribute__((address_space(1))) void*)(gwl + (size_t)(64 * i) * H + k0),
                (__attribute__((address_space(3))) void*)&dl[(wv * 8 + 64 * i) * 64], 16, 0, 0);
        }
    };

    auto kstep = [&](float4& xa, float4& xb, const unsigned short* bufh,
                     const unsigned short* bufl, unsigned short* nbufh,
                     unsigned short* nbufl, int ktw, int ktx) {
        const float xv[8] = {xa.x, xa.y, xa.z, xa.w, xb.x, xb.y, xb.z, xb.w};
        short8 h8, l8;
        #pragma unroll
        for (int j = 0; j < 8; ++j) {
            unsigned short h = f2bf(xv[j]);
            h8[j] = (short)h;
            l8[j] = (short)f2bf(xv[j] - bf2f(h));
        }
        *(short8*)&xh[xrow * 64 + xpos * 8] = h8;
        *(short8*)&xl[xrow * 64 + xpos * 8] = l8;
        asm volatile("s_waitcnt vmcnt(2) lgkmcnt(0)" ::: "memory");
        __builtin_amdgcn_sched_barrier(0);
        __builtin_amdgcn_s_barrier();
        short8 fAh[2][2], fAl[2][2], fBh[2][4], fBl[2][4];
        #pragma unroll
        for (int kk = 0; kk < 2; ++kk) {
            const int cc = ((kk * 4 + fq) ^ (fr & 7)) * 8;
            #pragma unroll
            for (int mt = 0; mt < 2; ++mt) {
                const int r = wr * 32 + mt * 16 + fr;
                fAh[kk][mt] = *(const short8*)&xh[r * 64 + cc];
                fAl[kk][mt] = *(const short8*)&xl[r * 64 + cc];
            }
            #pragma unroll
            for (int nt = 0; nt < 4; ++nt) {
                const int r = wc * 64 + nt * 16 + fr;
                fBh[kk][nt] = *(const short8*)&bufh[r * 64 + cc];
                fBl[kk][nt] = *(const short8*)&bufl[r * 64 + cc];
            }
        }
        asm volatile("s_waitcnt lgkmcnt(0)" ::: "memory");
        __builtin_amdgcn_sched_barrier(0);
        __builtin_amdgcn_s_barrier();
        issueW(nbufh, nbufl, ktw);
        __builtin_amdgcn_sched_barrier(0);
        xa = *(const float4*)(gx + (size_t)ktx * 64);
        xb = *(const float4*)(gx + (size_t)ktx * 64 + 4);
        __builtin_amdgcn_sched_barrier(0);
        __builtin_amdgcn_s_setprio(1);
        #pragma unroll
        for (int kk = 0; kk < 2; ++kk)
            #pragma unroll
            for (int mt = 0; mt < 2; ++mt)
                #pragma unroll
                for (int nt = 0; nt < 4; ++nt) {
                    acc[mt][nt] = __builtin_amdgcn_mfma_f32_16x16x32_bf16(fAh[kk][mt], fBh[kk][nt], acc[mt][nt], 0, 0, 0);
                    acc[mt][nt] = __builtin_amdgcn_mfma_f32_16x16x32_bf16(fAh[kk][mt], fBl[kk][nt], acc[mt][nt], 0, 0, 0);
                    acc[mt][nt] = __builtin_amdgcn_mfma_f32_16x16x32_bf16(fAl[kk][mt], fBh[kk][nt], acc[mt][nt], 0, 0, 0);
                }
        __builtin_amdgcn_s_setprio(0);
    };

    issueW(wh0, wl0, 0);
    __builtin_amdgcn_sched_barrier(0);
    float4 x0a = *(const float4*)(gx);
    float4 x0b = *(const float4*)(gx + 4);
    float4 x1a = *(const float4*)(gx + 64);
    float4 x1b = *(const float4*)(gx + 64 + 4);

    for (int kt = 0; kt < 64; kt += 2) {
        const int k1 = kt + 1;
        const int k2 = (kt + 2 < 64) ? kt + 2 : 0;
        const int k3 = (kt + 3 < 64) ? kt + 3 : 0;
        kstep(x0a, x0b, wh0, wl0, wh1, wl1, (k1 < 64) ? k1 : 0, k2);
        kstep(x1a, x1b, wh1, wl1, wh0, wl0, k2, k3);
    }
    asm volatile("" :: "v"(x0a.x), "v"(x0b.x), "v"(x1a.x), "v"(x1b.x));
    asm volatile("s_waitcnt vmcnt(0) lgkmcnt(0)" ::: "memory");
    __builtin_amdgcn_sched_barrier(0);
    __builtin_amdgcn_s_barrier();

    float* Ls = (float*)(smem + 8192);
    #pragma unroll
    for (int mt = 0; mt < 2; ++mt)
        #pragma unroll
        for (int nt = 0; nt < 4; ++nt)
            #pragma unroll
            for (int r = 0; r < 4; ++r)
                Ls[(wr * 32 + mt * 16 + fq * 4 + r) * 260 + (wc * 64 + nt * 16 + fr)] = acc[mt][nt][r];
    __syncthreads();

    const float4 bf4 = *(const float4*)(bias + lane * 4);
    const float bfa[4] = {bf4.x, bf4.y, bf4.z, bf4.w};

    #pragma unroll 1
    for (int tt = 0; tt < 8; ++tt) {
        const int tok = wv * 8 + tt;
        const float4 lg = *(const float4*)&Ls[tok * 260 + lane * 4];
        const float lga[4] = {lg.x, lg.y, lg.z, lg.w};
        float s[4], sc[4];
        #pragma unroll
        for (int i = 0; i < 4; ++i) {
            s[i] = 1.f / (1.f + expf(-lga[i]));
            sc[i] = s[i] + bfa[i];
        }
        float a1 = fmaxf(sc[0], sc[1]), a2 = fminf(sc[0], sc[1]);
        float b1 = fmaxf(sc[2], sc[3]), b2 = fminf(sc[2], sc[3]);
        float t1 = fmaxf(a1, b1);
        float t2 = fmaxf(fminf(a1, b1), fmaxf(a2, b2));
        #pragma unroll
        for (int off = 1; off <= 4; off <<= 1) {
            float o1 = __shfl_xor(t1, off, 64);
            float o2 = __shfl_xor(t2, off, 64);
            float n1 = fmaxf(t1, o1);
            float n2 = fmaxf(fminf(t1, o1), fmaxf(t2, o2));
            t1 = n1; t2 = n2;
        }
        const float gsum = t1 + t2;
        float gsv[8];
        #pragma unroll
        for (int g = 0; g < 8; ++g) gsv[g] = __shfl(gsum, g * 8, 64);

        float minsel = 3e38f, maxuns = -3e38f;
        bool sel = false;
        const int myg = lane >> 3;
        #pragma unroll
        for (int g = 0; g < 8; ++g) {
            int cg = 0;
            #pragma unroll
            for (int g2 = 0; g2 < 8; ++g2)
                cg += (gsv[g2] > gsv[g] || (gsv[g2] == gsv[g] && g2 < g)) ? 1 : 0;
            const bool sg = (cg < 4);
            if (sg) minsel = fminf(minsel, gsv[g]); else maxuns = fmaxf(maxuns, gsv[g]);
            if (myg == g) sel = sg;
        }
        bool flag = (minsel - maxuns) < EPS_G;

        float v[4];
        #pragma unroll
        for (int i = 0; i < 4; ++i) v[i] = sel ? sc[i] : 0.f;

        int idxs[8]; float sigs[8];
        float denom = 0.f, prevv = 0.f;
        #pragma unroll
        for (int r = 0; r < 9; ++r) {
            float bv = v[0]; int bi = 0; float bs = s[0];
            #pragma unroll
            for (int i = 1; i < 4; ++i)
                if (v[i] > bv) { bv = v[i]; bi = i; bs = s[i]; }
            int bidx = (lane << 2) + bi;
            #pragma unroll
            for (int off = 1; off < 64; off <<= 1) {
                float ov = __shfl_xor(bv, off, 64);
                int  oi = __shfl_xor(bidx, off, 64);
                float os = __shfl_xor(bs, off, 64);
                if (ov > bv || (ov == bv && oi < bidx)) { bv = ov; bidx = oi; bs = os; }
            }
            if (r > 0) flag = flag || ((prevv - bv) < EPS_E);
            prevv = bv;
            if (r < 8) {
                idxs[r] = bidx; sigs[r] = bs; denom += bs;
                if ((bidx >> 2) == lane) {
                    #pragma unroll
                    for (int i = 0; i < 4; ++i)
                        if ((bidx & 3) == i) v[i] = -3e38f;
                }
            }
        }
        denom += 1e-20f;
        const int n = m0 + tok;
        #pragma unroll
        for (int r = 0; r < 8; ++r)
            if (lane == r) {
                out[n * 8 + r] = (float)idxs[r];
                out[NTOK * 8 + n * 8 + r] = sigs[r] / denom * 2.5f;
            }
        if (flag && lane == 0) {
            int slot = atomicAdd(ws, 1);
            if (slot < cap) ws[16 + slot] = n;
        }
    }
}

// old 1-token fixup (for fused fallback path)
__global__ __launch_bounds__(256)
void moe_fix(const float* __restrict__ X, const float* __restrict__ W,
             const float* __restrict__ bias, float* __restrict__ out,
             const int* __restrict__ ws, int cap)
{
    __shared__ double Xd[H];
    __shared__ double Ld[NE];
    const int t = threadIdx.x;
    const int lane = t & 63;
    const int wv = t >> 6;
    int count = ws[0]; if (count > cap) count = cap;

    for (int i = blockIdx.x; i < count; i += (int)gridDim.x) {
        const int n = ws[16 + i];
        __syncthreads();
        const float* xrow = X + (size_t)n * H;
        for (int k = t * 4; k < H; k += 1024) {
            float4 x4 = *(const float4*)(xrow + k);
            Xd[k] = (double)x4.x; Xd[k + 1] = (double)x4.y;
            Xd[k + 2] = (double)x4.z; Xd[k + 3] = (double)x4.w;
        }
        __syncthreads();
        #pragma unroll 1
        for (int cc = 0; cc < 16; ++cc) {
            const int e0 = wv * 64 + cc * 4;
            double a[4] = {0.0, 0.0, 0.0, 0.0};
            for (int j = 0; j < 16; ++j) {
                const int kb = (lane + 64 * j) * 4;
                const double x0 = Xd[kb], x1 = Xd[kb + 1], x2 = Xd[kb + 2], x3 = Xd[kb + 3];
                #pragma unroll
                for (int ee = 0; ee < 4; ++ee) {
                    float4 w4 = *(const float4*)(W + (size_t)(e0 + ee) * H + kb);
                    a[ee] = fma(x0, (double)w4.x, a[ee]);
                    a[ee] = fma(x1, (double)w4.y, a[ee]);
                    a[ee] = fma(x2, (double)w4.z, a[ee]);
                    a[ee] = fma(x3, (double)w4.w, a[ee]);
                }
            }
            #pragma unroll
            for (int ee = 0; ee < 4; ++ee)
                #pragma unroll
                for (int off = 1; off < 64; off <<= 1)
                    a[ee] += __shfl_xor(a[ee], off, 64);
            if (lane == 0) { Ld[e0] = a[0]; Ld[e0 + 1] = a[1]; Ld[e0 + 2] = a[2]; Ld[e0 + 3] = a[3]; }
        }
        __syncthreads();
        if (wv == 0) {
            double s[4], sc[4];
            #pragma unroll
            for (int ii = 0; ii < 4; ++ii) {
                const double L = Ld[lane * 4 + ii];
                s[ii] = 1.0 / (1.0 + exp(-L));
                sc[ii] = s[ii] + (double)bias[lane * 4 + ii];
            }
            double a1 = fmax(sc[0], sc[1]), a2 = fmin(sc[0], sc[1]);
            double b1 = fmax(sc[2], sc[3]), b2 = fmin(sc[2], sc[3]);
            double t1 = fmax(a1, b1);
            double t2 = fmax(fmin(a1, b1), fmax(a2, b2));
            #pragma unroll
            for (int off = 1; off <= 4; off <<= 1) {
                double o1 = __shfl_xor(t1, off, 64);
                double o2 = __shfl_xor(t2, off, 64);
                double n1 = fmax(t1, o1);
                double n2 = fmax(fmin(t1, o1), fmax(t2, o2));
                t1 = n1; t2 = n2;
            }
            const double gsum = t1 + t2;
            double gsv[8];
            #pragma unroll
            for (int g = 0; g < 8; ++g) gsv[g] = __shfl(gsum, g * 8, 64);
            const int myg = lane >> 3;
            int cnt = 0;
            #pragma unroll
            for (int g = 0; g < 8; ++g)
                cnt += (gsv[g] > gsum || (gsv[g] == gsum && g < myg)) ? 1 : 0;
            const bool sel = (cnt < 4);
            double v[4];
            #pragma unroll
            for (int ii = 0; ii < 4; ++ii) v[ii] = sel ? sc[ii] : 0.0;
            int idxs[8]; double sigs[8];
            double denom = 0.0;
            #pragma unroll
            for (int r = 0; r < 8; ++r) {
                double bv = v[0]; int bi = 0; double bs = s[0];
                #pragma unroll
                for (int ii = 1; ii < 4; ++ii)
                    if (v[ii] > bv) { bv = v[ii]; bi = ii; bs = s[ii]; }
                int bidx = (lane << 2) + bi;
                #pragma unroll
                for (int off = 1; off < 64; off <<= 1) {
                    double ov = __shfl_xor(bv, off, 64);
                    int oi = __shfl_xor(bidx, off, 64);
                    double os = __shfl_xor(bs, off, 64);
                    if (ov > bv || (ov == bv && oi < bidx)) { bv = ov; bidx = oi; bs = os; }
                }
                idxs[r] = bidx; sigs[r] = bs; denom += bs;
                if ((bidx >> 2) == lane) {
                    #pragma unroll
                    for (int ii = 0; ii < 4; ++ii)
                        if ((bidx & 3) == ii) v[ii] = -1.0e300;
                }
            }
            denom += 1e-20;
            #pragma unroll
            for (int r = 0; r < 8; ++r)
                if (lane == r) {
                    out[n * 8 + r] = (float)idxs[r];
                    out[NTOK * 8 + n * 8 + r] = (float)(sigs[r] / denom * 2.5);
                }
        }
    }
}

// low fallback: exact fp64 (slow but correct)
#define FXP 34
#define FEP 260
__global__ __launch_bounds__(256)
void moe_fb(const float* __restrict__ X, const float* __restrict__ W,
            const float* __restrict__ bias, float* __restrict__ out)
{
    __shared__ double Xs[16 * FXP];
    __shared__ double Ws[16 * FEP];
    const int t = threadIdx.x;
    const int lane = t & 63;
    const int wv = t >> 6;
    const int m0 = blockIdx.x * 32;
    double acc[8][4];
    #pragma unroll
    for (int i = 0; i < 8; ++i)
        #pragma unroll
        for (int j = 0; j < 4; ++j) acc[i][j] = 0.0;
    const int xm = t >> 3, xk = (t & 7) * 2;
    const int we = t >> 2, wk = (t & 3) * 4;
    const float* gx = X + (size_t)(m0 + xm) * H + xk;
    const float* gw = W + (size_t)we * H + wk;
    float2 xreg = *(const float2*)(gx);
    float4 wreg[4];
    #pragma unroll
    for (int p = 0; p < 4; ++p) wreg[p] = *(const float4*)(gw + (size_t)(64 * p) * H);
    const int NT = H / 16;
    for (int t0 = 0; t0 < NT; ++t0) {
        __syncthreads();
        Xs[(xk + 0) * FXP + xm] = (double)xreg.x;
        Xs[(xk + 1) * FXP + xm] = (double)xreg.y;
        #pragma unroll
        for (int p = 0; p < 4; ++p) {
            const int e = we + 64 * p;
            Ws[(wk + 0) * FEP + e] = (double)wreg[p].x;
            Ws[(wk + 1) * FEP + e] = (double)wreg[p].y;
            Ws[(wk + 2) * FEP + e] = (double)wreg[p].z;
            Ws[(wk + 3) * FEP + e] = (double)wreg[p].w;
        }
        __syncthreads();
        if (t0 + 1 < NT) {
            const int off = (t0 + 1) * 16;
            xreg = *(const float2*)(gx + off);
            #pragma unroll
            for (int p = 0; p < 4; ++p) wreg[p] = *(const float4*)(gw + (size_t)(64 * p) * H + off);
        }
        #pragma unroll
        for (int j = 0; j < 16; ++j) {
            const double* xrow = &Xs[j * FXP + wv * 8];
            const double2 wa = *(const double2*)&Ws[j * FEP + lane * 4];
            const double2 wb = *(const double2*)&Ws[j * FEP + lane * 4 + 2];
            const double ws4[4] = {wa.x, wa.y, wb.x, wb.y};
            #pragma unroll
            for (int mi = 0; mi < 8; ++mi)
                #pragma unroll
                for (int ei = 0; ei < 4; ++ei)
                    acc[mi][ei] = fma(xrow[mi], ws4[ei], acc[mi][ei]);
        }
    }
    const float4 bf = *(const float4*)(bias + lane * 4);
    const double bfa[4] = {(double)bf.x, (double)bf.y, (double)bf.z, (double)bf.w};
    #pragma unroll 1
    for (int tt = 0; tt < 8; ++tt) {
        double s[4], sc[4];
        #pragma unroll
        for (int i = 0; i < 4; ++i) {
            s[i] = 1.0 / (1.0 + exp(-acc[tt][i]));
            sc[i] = s[i] + bfa[i];
        }
        double a1 = fmax(sc[0], sc[1]), a2 = fmin(sc[0], sc[1]);
        double b1 = fmax(sc[2], sc[3]), b2 = fmin(sc[2], sc[3]);
        double t1 = fmax(a1, b1);
        double t2 = fmax(fmin(a1, b1), fmax(a2, b2));
        #pragma unroll
        for (int off = 1; off <= 4; off <<= 1) {
            double o1 = __shfl_xor(t1, off, 64);
            double o2 = __shfl_xor(t2, off, 64);
            double n1 = fmax(t1, o1);
            double n2 = fmax(fmin(t1, o1), fmax(t2, o2));
            t1 = n1; t2 = n2;
        }
        const double gsum = t1 + t2;
        double gsv[8];
        #pragma unroll
        for (int g = 0; g < 8; ++g) gsv[g] = __shfl(gsum, g * 8, 64);
        const int myg = lane >> 3;
        int cnt = 0;
        #pragma unroll
        for (int g = 0; g < 8; ++g)
            cnt += (gsv[g] > gsum || (gsv[g] == gsum && g < myg)) ? 1 : 0;
        const bool sel = (cnt < 4);
        double v[4];
        #pragma unroll
        for (int i = 0; i < 4; ++i) v[i] = sel ? sc[i] : 0.0;
        int idxs[8]; double sigs[8];
        double denom = 0.0;
        #pragma unroll
        for (int r = 0; r < 8; ++r) {
            double bv = v[0]; int bi = 0; double bs = s[0];
            #pragma unroll
            for (int i = 1; i < 4; ++i)
                if (v[i] > bv) { bv = v[i]; bi = i; bs = s[i]; }
            int bidx = (lane << 2) + bi;
            #pragma unroll
            for (int off = 1; off < 64; off <<= 1) {
                double ov = __shfl_xor(bv, off, 64);
                int oi = __shfl_xor(bidx, off, 64);
                double os = __shfl_xor(bs, off, 64);
                if (ov > bv || (ov == bv && oi < bidx)) { bv = ov; bidx = oi; bs = os; }
            }
            idxs[r] = bidx; sigs[r] = bs; denom += bs;
            if ((bidx >> 2) == lane) {
                #pragma unroll
                for (int i = 0; i < 4; ++i)
                    if ((bidx & 3) == i) v[i] = -1.0e300;
            }
        }
        denom += 1e-20;
        const size_t n = (size_t)(m0 + wv * 8 + tt);
        #pragma unroll
        for (int r = 0; r < 8; ++r)
            if (lane == r) {
                out[n * 8 + r] = (float)idxs[r];
                out[(size_t)NTOK * 8 + n * 8 + r] = (float)(sigs[r] / denom * 2.5);
            }
    }
}

extern "C" void kernel_launch(void* const* d_in, const int* in_sizes, int n_in,
                              void* d_out, int out_size, void* d_ws, size_t ws_size,
                              hipStream_t stream) {
    const float* X = (const float*)d_in[0];
    const float* W = (const float*)d_in[1];
    const float* bias = (const float*)d_in[2];
    float* out = (float*)d_out;

    const size_t WB = (size_t)NE * H * 2;
    const size_t OFF_W = 65536;
    const size_t OFF_FIX = OFF_W + 2 * WB;
    const size_t FIXB = (size_t)FIXCAP * NE * 8;
    const size_t OFF_LOG = OFF_FIX + FIXB;
    const size_t NEED1 = OFF_FIX;
    const size_t minlog = (size_t)256 * NE * 4;

    if (ws_size < NEED1) {
        moe_fb<<<NTOK / 32, 256, 0, stream>>>(X, W, bias, out);
        return;
    }
    int* ws = (int*)d_ws;
    unsigned short* whi = (unsigned short*)((char*)d_ws + OFF_W);
    unsigned short* wlo = whi + (size_t)NE * H;

    zero_ws<<<1, 64, 0, stream>>>(ws);
    split_w<<<(NE * H) / 1024, 256, 0, stream>>>(W, whi, wlo);

    if (ws_size >= OFF_LOG + minlog) {
        double* fixlog = (double*)((char*)d_ws + OFF_FIX);
        float* logits = (float*)((char*)d_ws + OFF_LOG);
        const size_t avail = ws_size - OFF_LOG;
        size_t full = (size_t)NTOK * NE * 4;
        int CT;
        if (avail >= full) CT = NTOK;
        else {
            CT = (int)(avail / ((size_t)NE * 4));
            CT &= ~255;
        }
        for (int mb0 = 0; mb0 < NTOK; mb0 += CT) {
            int ct = (NTOK - mb0 < CT) ? (NTOK - mb0) : CT;
            gemm3<<<(ct / 32) * 2, 256, 0, stream>>>(X, whi, wlo, logits, mb0);
            route<<<ct / 32, 256, 0, stream>>>(logits, bias, out, ws, FLAGCAP, mb0);
        }
        fix1<<<2048, 256, 0, stream>>>(X, W, ws, fixlog, FIXCAP);
        fix2<<<256, 256, 0, stream>>>(fixlog, bias, out, ws, FIXCAP);
    } else {
        moe_fused<<<NTOK / 64, 512, 0, stream>>>(X, whi, wlo, bias, out, ws, FLAGCAP);
        moe_fix<<<1024, 256, 0, stream>>>(X, W, bias, out, ws, FLAGCAP);
    }
}

// Round 14
// 221.989 us; speedup vs baseline: 1.1664x; 1.1570x over previous
//
#include <hip/hip_runtime.h>
#include <math.h>

#define NTOK 16384
#define H 4096
#define NE 256
#define EPS_E 1.2e-5f
#define EPS_G 2.4e-5f
#define FIXCAP 1024
#define FLAGCAP 8192

typedef __attribute__((ext_vector_type(8))) short short8;
typedef __attribute__((ext_vector_type(4))) float f32x4;

__device__ __forceinline__ unsigned short f2bf(float x) {
    union { float f; unsigned u; } v; v.f = x;
    unsigned r = v.u + 0x7FFF + ((v.u >> 16) & 1);
    return (unsigned short)(r >> 16);
}
__device__ __forceinline__ float bf2f(unsigned short h) {
    union { float f; unsigned u; } v; v.u = ((unsigned)h) << 16;
    return v.f;
}

__global__ __launch_bounds__(256)
void split_w(const float* __restrict__ W, unsigned short* __restrict__ whi,
             unsigned short* __restrict__ wlo, int* __restrict__ ws)
{
    if (blockIdx.x == 0 && threadIdx.x == 0) ws[0] = 0;
    const int i = (blockIdx.x * 256 + threadIdx.x) * 4;
    float4 w4 = *(const float4*)(W + i);
    const float wv[4] = {w4.x, w4.y, w4.z, w4.w};
    ushort4 hh, ll;
    unsigned short* hp = (unsigned short*)&hh;
    unsigned short* lp = (unsigned short*)&ll;
    #pragma unroll
    for (int j = 0; j < 4; ++j) {
        unsigned short h = f2bf(wv[j]);
        hp[j] = h;
        lp[j] = f2bf(wv[j] - bf2f(h));
    }
    *(ushort4*)(whi + i) = hh;
    *(ushort4*)(wlo + i) = ll;
}

// ============ Stage 1 (R8-verified config): BM=64 x BN=128, 48KB, 3 blocks/CU ============
__global__ __launch_bounds__(256, 3)
void gemm3(const float* __restrict__ X, const unsigned short* __restrict__ Whi,
           const unsigned short* __restrict__ Wlo, float* __restrict__ logits,
           int m_base)
{
    __shared__ __align__(16) unsigned short smem[24576];  // 48 KB
    unsigned short* Ah = smem;              // [64][64] bf16 swizzled
    unsigned short* Al = smem + 4096;
    unsigned short* Bh = smem + 8192;       // [128][64]
    unsigned short* Bl = smem + 16384;

    const int t = threadIdx.x;
    const int lane = t & 63;
    const int w = t >> 6;                   // 0..3
    const int wm = w >> 1, wn = w & 1;
    const int fr = lane & 15, fq = lane >> 4;

    const int G = (int)gridDim.x;
    const int swz = (blockIdx.x & 7) * (G >> 3) + (blockIdx.x >> 3);
    const int nb = swz & 1;
    const int mb = swz >> 1;
    const int mloc = mb * 64;
    const int m0 = m_base + mloc;
    const int e0 = nb * 128;

    f32x4 acc[2][4];
    #pragma unroll
    for (int a = 0; a < 2; ++a)
        #pragma unroll
        for (int b = 0; b < 4; ++b) acc[a][b] = (f32x4){0.f, 0.f, 0.f, 0.f};

    // A staging: thread t -> row ar (0..63), 16 contiguous floats at chunk akc
    const int ar = t >> 2;
    const int akc = t & 3;
    const float* gxa = X + (size_t)(m0 + ar) * H + akc * 16;

    // B staging via global_load_lds (linear dest, pre-swizzled source)
    const int blr = lane >> 3;
    const int bsrc = (lane & 7) ^ blr;
    const unsigned short* gbh = Whi + (size_t)(e0 + w * 8 + blr) * H + bsrc * 8;
    const unsigned short* gbl = Wlo + (size_t)(e0 + w * 8 + blr) * H + bsrc * 8;

    float4 xr0, xr1, xr2, xr3;
    auto loadX = [&](int kt) {
        const float* p = gxa + (size_t)kt * 64;
        xr0 = *(const float4*)p;       xr1 = *(const float4*)(p + 4);
        xr2 = *(const float4*)(p + 8); xr3 = *(const float4*)(p + 12);
    };

    loadX(0);   // X(0) in flight: 4 loads

    #pragma unroll 1
    for (int kt = 0; kt < 64; ++kt) {
        // all waves done reading previous tile
        __builtin_amdgcn_sched_barrier(0);
        __builtin_amdgcn_s_barrier();
        __builtin_amdgcn_sched_barrier(0);
        // issue B(kt): 8 gload_lds (in-flight: X 4 old + B 8 new)
        const size_t k0 = (size_t)kt * 64;
        #pragma unroll
        for (int i = 0; i < 4; ++i) {
            __builtin_amdgcn_global_load_lds(
                (const __attribute__((address_space(1))) void*)(gbh + (size_t)(32 * i) * H + k0),
                (__attribute__((address_space(3))) void*)&Bh[(w * 8 + 32 * i) * 64], 16, 0, 0);
            __builtin_amdgcn_global_load_lds(
                (const __attribute__((address_space(1))) void*)(gbl + (size_t)(32 * i) * H + k0),
                (__attribute__((address_space(3))) void*)&Bl[(w * 8 + 32 * i) * 64], 16, 0, 0);
        }
        __builtin_amdgcn_sched_barrier(0);
        // X(kt) regs ready (drain the 4 oldest; B stays in flight)
        asm volatile("s_waitcnt vmcnt(8)" ::: "memory");
        __builtin_amdgcn_sched_barrier(0);
        // split X(kt) (truncation split) -> swizzled A LDS writes
        {
            const float xf[16] = {xr0.x, xr0.y, xr0.z, xr0.w, xr1.x, xr1.y, xr1.z, xr1.w,
                                  xr2.x, xr2.y, xr2.z, xr2.w, xr3.x, xr3.y, xr3.z, xr3.w};
            short8 h0, h1, l0, l1;
            #pragma unroll
            for (int j = 0; j < 16; ++j) {
                union { float f; unsigned u; } uu; uu.f = xf[j];
                union { unsigned u; float f; } hh; hh.u = uu.u & 0xFFFF0000u;
                union { float f; unsigned u; } ll; ll.f = xf[j] - hh.f;
                unsigned short hs = (unsigned short)(uu.u >> 16);
                unsigned short ls = (unsigned short)(ll.u >> 16);
                if (j < 8) { h0[j] = (short)hs; l0[j] = (short)ls; }
                else       { h1[j - 8] = (short)hs; l1[j - 8] = (short)ls; }
            }
            const int c0 = akc * 2;
            const int p0 = (c0 ^ (ar & 7)) * 8, p1 = ((c0 + 1) ^ (ar & 7)) * 8;
            *(short8*)&Ah[ar * 64 + p0] = h0;
            *(short8*)&Ah[ar * 64 + p1] = h1;
            *(short8*)&Al[ar * 64 + p0] = l0;
            *(short8*)&Al[ar * 64 + p1] = l1;
        }
        // prefetch X(kt+1) (kept in flight across the barrier)
        loadX(kt + 1 < 64 ? kt + 1 : 63);
        __builtin_amdgcn_sched_barrier(0);
        // B(kt) landed + A writes visible; X(kt+1) stays in flight
        asm volatile("s_waitcnt vmcnt(4) lgkmcnt(0)" ::: "memory");
        __builtin_amdgcn_sched_barrier(0);
        __builtin_amdgcn_s_barrier();
        __builtin_amdgcn_sched_barrier(0);
        // compute: 48 MFMAs/wave
        #pragma unroll
        for (int kk = 0; kk < 2; ++kk) {
            short8 ah[2], al[2], bh[4], bl[4];
            #pragma unroll
            for (int mt = 0; mt < 2; ++mt) {
                const int r = wm * 32 + mt * 16 + fr;
                const int pos = ((kk * 4 + fq) ^ (r & 7)) * 8;
                ah[mt] = *(const short8*)&Ah[r * 64 + pos];
                al[mt] = *(const short8*)&Al[r * 64 + pos];
            }
            #pragma unroll
            for (int nt = 0; nt < 4; ++nt) {
                const int r = wn * 64 + nt * 16 + fr;
                const int pos = ((kk * 4 + fq) ^ (r & 7)) * 8;
                bh[nt] = *(const short8*)&Bh[r * 64 + pos];
                bl[nt] = *(const short8*)&Bl[r * 64 + pos];
            }
            #pragma unroll
            for (int mt = 0; mt < 2; ++mt)
                #pragma unroll
                for (int nt = 0; nt < 4; ++nt)
                    acc[mt][nt] = __builtin_amdgcn_mfma_f32_16x16x32_bf16(ah[mt], bh[nt], acc[mt][nt], 0, 0, 0);
            #pragma unroll
            for (int mt = 0; mt < 2; ++mt)
                #pragma unroll
                for (int nt = 0; nt < 4; ++nt)
                    acc[mt][nt] = __builtin_amdgcn_mfma_f32_16x16x32_bf16(ah[mt], bl[nt], acc[mt][nt], 0, 0, 0);
            #pragma unroll
            for (int mt = 0; mt < 2; ++mt)
                #pragma unroll
                for (int nt = 0; nt < 4; ++nt)
                    acc[mt][nt] = __builtin_amdgcn_mfma_f32_16x16x32_bf16(al[mt], bh[nt], acc[mt][nt], 0, 0, 0);
        }
    }
    // keep tail X prefetch alive so per-iter vmcnt counts stay exact
    asm volatile("" :: "v"(xr0.x), "v"(xr1.x), "v"(xr2.x), "v"(xr3.x));

    // store logits (local token index)
    #pragma unroll
    for (int mt = 0; mt < 2; ++mt)
        #pragma unroll
        for (int nt = 0; nt < 4; ++nt)
            #pragma unroll
            for (int r = 0; r < 4; ++r)
                logits[(size_t)(mloc + wm * 32 + mt * 16 + fq * 4 + r) * NE +
                       (e0 + wn * 64 + nt * 16 + fr)] = acc[mt][nt][r];
}

// ============ Stage 2: routing from fp32 logits (verified epilogue) ============
__global__ __launch_bounds__(256)
void route(const float* __restrict__ logits, const float* __restrict__ bias,
           float* __restrict__ out, int* __restrict__ ws, int cap, int m_base)
{
    const int t = threadIdx.x, lane = t & 63, wv = t >> 6;
    const float4 bf4 = *(const float4*)(bias + lane * 4);
    const float bfa[4] = {bf4.x, bf4.y, bf4.z, bf4.w};

    #pragma unroll 1
    for (int tt = 0; tt < 8; ++tt) {
        const int local = blockIdx.x * 32 + wv * 8 + tt;
        const int n = m_base + local;
        const float4 lg = *(const float4*)&logits[(size_t)local * NE + lane * 4];
        const float lga[4] = {lg.x, lg.y, lg.z, lg.w};
        float s[4], sc[4];
        #pragma unroll
        for (int i = 0; i < 4; ++i) {
            s[i] = 1.f / (1.f + expf(-lga[i]));
            sc[i] = s[i] + bfa[i];
        }
        float a1 = fmaxf(sc[0], sc[1]), a2 = fminf(sc[0], sc[1]);
        float b1 = fmaxf(sc[2], sc[3]), b2 = fminf(sc[2], sc[3]);
        float t1 = fmaxf(a1, b1);
        float t2 = fmaxf(fminf(a1, b1), fmaxf(a2, b2));
        #pragma unroll
        for (int off = 1; off <= 4; off <<= 1) {
            float o1 = __shfl_xor(t1, off, 64);
            float o2 = __shfl_xor(t2, off, 64);
            float n1 = fmaxf(t1, o1);
            float n2 = fmaxf(fminf(t1, o1), fmaxf(t2, o2));
            t1 = n1; t2 = n2;
        }
        const float gsum = t1 + t2;
        float gsv[8];
        #pragma unroll
        for (int g = 0; g < 8; ++g) gsv[g] = __shfl(gsum, g * 8, 64);

        float minsel = 3e38f, maxuns = -3e38f;
        bool sel = false;
        const int myg = lane >> 3;
        #pragma unroll
        for (int g = 0; g < 8; ++g) {
            int cg = 0;
            #pragma unroll
            for (int g2 = 0; g2 < 8; ++g2)
                cg += (gsv[g2] > gsv[g] || (gsv[g2] == gsv[g] && g2 < g)) ? 1 : 0;
            const bool sg = (cg < 4);
            if (sg) minsel = fminf(minsel, gsv[g]); else maxuns = fmaxf(maxuns, gsv[g]);
            if (myg == g) sel = sg;
        }
        bool flag = (minsel - maxuns) < EPS_G;

        float v[4];
        #pragma unroll
        for (int i = 0; i < 4; ++i) v[i] = sel ? sc[i] : 0.f;

        int idxs[8]; float sigs[8];
        float denom = 0.f, prevv = 0.f;
        #pragma unroll
        for (int r = 0; r < 9; ++r) {
            float bv = v[0]; int bi = 0; float bs = s[0];
            #pragma unroll
            for (int i = 1; i < 4; ++i)
                if (v[i] > bv) { bv = v[i]; bi = i; bs = s[i]; }
            int bidx = (lane << 2) + bi;
            #pragma unroll
            for (int off = 1; off < 64; off <<= 1) {
                float ov = __shfl_xor(bv, off, 64);
                int  oi = __shfl_xor(bidx, off, 64);
                float os = __shfl_xor(bs, off, 64);
                if (ov > bv || (ov == bv && oi < bidx)) { bv = ov; bidx = oi; bs = os; }
            }
            if (r > 0) flag = flag || ((prevv - bv) < EPS_E);
            prevv = bv;
            if (r < 8) {
                idxs[r] = bidx; sigs[r] = bs; denom += bs;
                if ((bidx >> 2) == lane) {
                    #pragma unroll
                    for (int i = 0; i < 4; ++i)
                        if ((bidx & 3) == i) v[i] = -3e38f;
                }
            }
        }
        denom += 1e-20f;
        #pragma unroll
        for (int r = 0; r < 8; ++r)
            if (lane == r) {
                out[n * 8 + r] = (float)idxs[r];
                out[NTOK * 8 + n * 8 + r] = sigs[r] / denom * 2.5f;
            }
        if (flag && lane == 0) {
            int slot = atomicAdd(ws, 1);
            if (slot < cap) ws[16 + slot] = n;
        }
    }
}

// ============ fp64 fixup stage A: exact logits, expert-parallel ============
__global__ __launch_bounds__(256)
void fix1(const float* __restrict__ X, const float* __restrict__ W,
          const int* __restrict__ ws, double* __restrict__ fixlog, int cap)
{
    __shared__ float Xs4[4][4096];
    const int t = threadIdx.x, lane = t & 63, wv = t >> 6;
    int count = ws[0]; if (count > cap) count = cap;
    const int ngrp = (count + 3) >> 2;

    for (int task = blockIdx.x; task < ngrp * 8; task += (int)gridDim.x) {
        const int g = task >> 3, er = task & 7;
        int tok[4];
        #pragma unroll
        for (int q = 0; q < 4; ++q) {
            const int idx = g * 4 + q;
            tok[q] = ws[16 + (idx < count ? idx : g * 4)];
        }
        __syncthreads();
        #pragma unroll
        for (int q = 0; q < 4; ++q)
            for (int k = t * 4; k < 4096; k += 1024)
                *(float4*)&Xs4[q][k] = *(const float4*)(X + (size_t)tok[q] * H + k);
        __syncthreads();
        #pragma unroll 1
        for (int cc = 0; cc < 2; ++cc) {
            const int eb = er * 32 + wv * 8 + cc * 4;
            double a[4][4];
            #pragma unroll
            for (int q = 0; q < 4; ++q)
                #pragma unroll
                for (int ee = 0; ee < 4; ++ee) a[q][ee] = 0.0;
            for (int j = 0; j < 16; ++j) {
                const int kb = (lane + 64 * j) * 4;
                double xx[4][4];
                #pragma unroll
                for (int q = 0; q < 4; ++q) {
                    float4 x4 = *(const float4*)&Xs4[q][kb];
                    xx[q][0] = x4.x; xx[q][1] = x4.y; xx[q][2] = x4.z; xx[q][3] = x4.w;
                }
                #pragma unroll
                for (int ee = 0; ee < 4; ++ee) {
                    float4 w4 = *(const float4*)(W + (size_t)(eb + ee) * H + kb);
                    const double wd[4] = {w4.x, w4.y, w4.z, w4.w};
                    #pragma unroll
                    for (int q = 0; q < 4; ++q)
                        #pragma unroll
                        for (int kq = 0; kq < 4; ++kq)
                            a[q][ee] = fma(xx[q][kq], wd[kq], a[q][ee]);
                }
            }
            #pragma unroll
            for (int q = 0; q < 4; ++q)
                #pragma unroll
                for (int ee = 0; ee < 4; ++ee) {
                    double v = a[q][ee];
                    #pragma unroll
                    for (int off = 1; off < 64; off <<= 1)
                        v += __shfl_xor(v, off, 64);
                    if (lane == 0) fixlog[(size_t)(g * 4 + q) * NE + eb + ee] = v;
                }
        }
    }
}

// ============ fp64 fixup stage B: routing from exact logits ============
__global__ __launch_bounds__(256)
void fix2(const double* __restrict__ fixlog, const float* __restrict__ bias,
          float* __restrict__ out, const int* __restrict__ ws, int cap)
{
    const int t = threadIdx.x, lane = t & 63, wv = t >> 6;
    int count = ws[0]; if (count > cap) count = cap;
    const int ngrp = (count + 3) >> 2;

    for (int g = blockIdx.x; g < ngrp; g += (int)gridDim.x) {
        const int idx = g * 4 + wv;
        const int slot = (idx < count) ? idx : g * 4;
        const int n = ws[16 + slot];
        const double* L = fixlog + (size_t)(g * 4 + wv) * NE;

        double s[4], sc[4];
        #pragma unroll
        for (int ii = 0; ii < 4; ++ii) {
            const double Lv = L[lane * 4 + ii];
            s[ii] = 1.0 / (1.0 + exp(-Lv));
            sc[ii] = s[ii] + (double)bias[lane * 4 + ii];
        }
        double a1 = fmax(sc[0], sc[1]), a2 = fmin(sc[0], sc[1]);
        double b1 = fmax(sc[2], sc[3]), b2 = fmin(sc[2], sc[3]);
        double t1 = fmax(a1, b1);
        double t2 = fmax(fmin(a1, b1), fmax(a2, b2));
        #pragma unroll
        for (int off = 1; off <= 4; off <<= 1) {
            double o1 = __shfl_xor(t1, off, 64);
            double o2 = __shfl_xor(t2, off, 64);
            double n1 = fmax(t1, o1);
            double n2 = fmax(fmin(t1, o1), fmax(t2, o2));
            t1 = n1; t2 = n2;
        }
        const double gsum = t1 + t2;
        double gsv[8];
        #pragma unroll
        for (int gg = 0; gg < 8; ++gg) gsv[gg] = __shfl(gsum, gg * 8, 64);
        const int myg = lane >> 3;
        int cnt = 0;
        #pragma unroll
        for (int gg = 0; gg < 8; ++gg)
            cnt += (gsv[gg] > gsum || (gsv[gg] == gsum && gg < myg)) ? 1 : 0;
        const bool sel = (cnt < 4);

        double v[4];
        #pragma unroll
        for (int ii = 0; ii < 4; ++ii) v[ii] = sel ? sc[ii] : 0.0;

        int idxs[8]; double sigs[8];
        double denom = 0.0;
        #pragma unroll
        for (int r = 0; r < 8; ++r) {
            double bv = v[0]; int bi = 0; double bs = s[0];
            #pragma unroll
            for (int ii = 1; ii < 4; ++ii)
                if (v[ii] > bv) { bv = v[ii]; bi = ii; bs = s[ii]; }
            int bidx = (lane << 2) + bi;
            #pragma unroll
            for (int off = 1; off < 64; off <<= 1) {
                double ov = __shfl_xor(bv, off, 64);
                int oi = __shfl_xor(bidx, off, 64);
                double os = __shfl_xor(bs, off, 64);
                if (ov > bv || (ov == bv && oi < bidx)) { bv = ov; bidx = oi; bs = os; }
            }
            idxs[r] = bidx; sigs[r] = bs; denom += bs;
            if ((bidx >> 2) == lane) {
                #pragma unroll
                for (int ii = 0; ii < 4; ++ii)
                    if ((bidx & 3) == ii) v[ii] = -1.0e300;
            }
        }
        denom += 1e-20;
        #pragma unroll
        for (int r = 0; r < 8; ++r)
            if (lane == r) {
                out[n * 8 + r] = (float)idxs[r];
                out[NTOK * 8 + n * 8 + r] = (float)(sigs[r] / denom * 2.5);
            }
    }
}

// low fallback: exact fp64 (slow but correct)
#define FXP 34
#define FEP 260
__global__ __launch_bounds__(256)
void moe_fb(const float* __restrict__ X, const float* __restrict__ W,
            const float* __restrict__ bias, float* __restrict__ out)
{
    __shared__ double Xs[16 * FXP];
    __shared__ double Ws[16 * FEP];
    const int t = threadIdx.x;
    const int lane = t & 63;
    const int wv = t >> 6;
    const int m0 = blockIdx.x * 32;
    double acc[8][4];
    #pragma unroll
    for (int i = 0; i < 8; ++i)
        #pragma unroll
        for (int j = 0; j < 4; ++j) acc[i][j] = 0.0;
    const int xm = t >> 3, xk = (t & 7) * 2;
    const int we = t >> 2, wk = (t & 3) * 4;
    const float* gx = X + (size_t)(m0 + xm) * H + xk;
    const float* gw = W + (size_t)we * H + wk;
    float2 xreg = *(const float2*)(gx);
    float4 wreg[4];
    #pragma unroll
    for (int p = 0; p < 4; ++p) wreg[p] = *(const float4*)(gw + (size_t)(64 * p) * H);
    const int NT = H / 16;
    for (int t0 = 0; t0 < NT; ++t0) {
        __syncthreads();
        Xs[(xk + 0) * FXP + xm] = (double)xreg.x;
        Xs[(xk + 1) * FXP + xm] = (double)xreg.y;
        #pragma unroll
        for (int p = 0; p < 4; ++p) {
            const int e = we + 64 * p;
            Ws[(wk + 0) * FEP + e] = (double)wreg[p].x;
            Ws[(wk + 1) * FEP + e] = (double)wreg[p].y;
            Ws[(wk + 2) * FEP + e] = (double)wreg[p].z;
            Ws[(wk + 3) * FEP + e] = (double)wreg[p].w;
        }
        __syncthreads();
        if (t0 + 1 < NT) {
            const int off = (t0 + 1) * 16;
            xreg = *(const float2*)(gx + off);
            #pragma unroll
            for (int p = 0; p < 4; ++p) wreg[p] = *(const float4*)(gw + (size_t)(64 * p) * H + off);
        }
        #pragma unroll
        for (int j = 0; j < 16; ++j) {
            const double* xrow = &Xs[j * FXP + wv * 8];
            const double2 wa = *(const double2*)&Ws[j * FEP + lane * 4];
            const double2 wb = *(const double2*)&Ws[j * FEP + lane * 4 + 2];
            const double ws4[4] = {wa.x, wa.y, wb.x, wb.y};
            #pragma unroll
            for (int mi = 0; mi < 8; ++mi)
                #pragma unroll
                for (int ei = 0; ei < 4; ++ei)
                    acc[mi][ei] = fma(xrow[mi], ws4[ei], acc[mi][ei]);
        }
    }
    const float4 bf = *(const float4*)(bias + lane * 4);
    const double bfa[4] = {(double)bf.x, (double)bf.y, (double)bf.z, (double)bf.w};
    #pragma unroll 1
    for (int tt = 0; tt < 8; ++tt) {
        double s[4], sc[4];
        #pragma unroll
        for (int i = 0; i < 4; ++i) {
            s[i] = 1.0 / (1.0 + exp(-acc[tt][i]));
            sc[i] = s[i] + bfa[i];
        }
        double a1 = fmax(sc[0], sc[1]), a2 = fmin(sc[0], sc[1]);
        double b1 = fmax(sc[2], sc[3]), b2 = fmin(sc[2], sc[3]);
        double t1 = fmax(a1, b1);
        double t2 = fmax(fmin(a1, b1), fmax(a2, b2));
        #pragma unroll
        for (int off = 1; off <= 4; off <<= 1) {
            double o1 = __shfl_xor(t1, off, 64);
            double o2 = __shfl_xor(t2, off, 64);
            double n1 = fmax(t1, o1);
            double n2 = fmax(fmin(t1, o1), fmax(t2, o2));
            t1 = n1; t2 = n2;
        }
        const double gsum = t1 + t2;
        double gsv[8];
        #pragma unroll
        for (int g = 0; g < 8; ++g) gsv[g] = __shfl(gsum, g * 8, 64);
        const int myg = lane >> 3;
        int cnt = 0;
        #pragma unroll
        for (int g = 0; g < 8; ++g)
            cnt += (gsv[g] > gsum || (gsv[g] == gsum && g < myg)) ? 1 : 0;
        const bool sel = (cnt < 4);
        double v[4];
        #pragma unroll
        for (int i = 0; i < 4; ++i) v[i] = sel ? sc[i] : 0.0;
        int idxs[8]; double sigs[8];
        double denom = 0.0;
        #pragma unroll
        for (int r = 0; r < 8; ++r) {
            double bv = v[0]; int bi = 0; double bs = s[0];
            #pragma unroll
            for (int i = 1; i < 4; ++i)
                if (v[i] > bv) { bv = v[i]; bi = i; bs = s[i]; }
            int bidx = (lane << 2) + bi;
            #pragma unroll
            for (int off = 1; off < 64; off <<= 1) {
                double ov = __shfl_xor(bv, off, 64);
                int oi = __shfl_xor(bidx, off, 64);
                double os = __shfl_xor(bs, off, 64);
                if (ov > bv || (ov == bv && oi < bidx)) { bv = ov; bidx = oi; bs = os; }
            }
            idxs[r] = bidx; sigs[r] = bs; denom += bs;
            if ((bidx >> 2) == lane) {
                #pragma unroll
                for (int i = 0; i < 4; ++i)
                    if ((bidx & 3) == i) v[i] = -1.0e300;
            }
        }
        denom += 1e-20;
        const size_t n = (size_t)(m0 + wv * 8 + tt);
        #pragma unroll
        for (int r = 0; r < 8; ++r)
            if (lane == r) {
                out[n * 8 + r] = (float)idxs[r];
                out[(size_t)NTOK * 8 + n * 8 + r] = (float)(sigs[r] / denom * 2.5);
            }
    }
}

extern "C" void kernel_launch(void* const* d_in, const int* in_sizes, int n_in,
                              void* d_out, int out_size, void* d_ws, size_t ws_size,
                              hipStream_t stream) {
    const float* X = (const float*)d_in[0];
    const float* W = (const float*)d_in[1];
    const float* bias = (const float*)d_in[2];
    float* out = (float*)d_out;

    const size_t WB = (size_t)NE * H * 2;
    const size_t OFF_W = 65536;
    const size_t OFF_FIX = OFF_W + 2 * WB;
    const size_t FIXB = (size_t)FIXCAP * NE * 8;
    const size_t OFF_LOG = OFF_FIX + FIXB;
    const size_t minlog = (size_t)256 * NE * 4;

    if (ws_size < OFF_LOG + minlog) {
        moe_fb<<<NTOK / 32, 256, 0, stream>>>(X, W, bias, out);
        return;
    }
    int* ws = (int*)d_ws;
    unsigned short* whi = (unsigned short*)((char*)d_ws + OFF_W);
    unsigned short* wlo = whi + (size_t)NE * H;
    double* fixlog = (double*)((char*)d_ws + OFF_FIX);
    float* logits = (float*)((char*)d_ws + OFF_LOG);

    split_w<<<(NE * H) / 1024, 256, 0, stream>>>(W, whi, wlo, ws);

    const size_t avail = ws_size - OFF_LOG;
    size_t full = (size_t)NTOK * NE * 4;
    int CT;
    if (avail >= full) CT = NTOK;
    else {
        CT = (int)(avail / ((size_t)NE * 4));
        CT &= ~255;
    }
    for (int mb0 = 0; mb0 < NTOK; mb0 += CT) {
        int ct = (NTOK - mb0 < CT) ? (NTOK - mb0) : CT;
        gemm3<<<(ct / 64) * 2, 256, 0, stream>>>(X, whi, wlo, logits, mb0);
        route<<<ct / 32, 256, 0, stream>>>(logits, bias, out, ws, FLAGCAP, mb0);
    }
    fix1<<<1024, 256, 0, stream>>>(X, W, ws, fixlog, FIXCAP);
    fix2<<<256, 256, 0, stream>>>(fixlog, bias, out, ws, FIXCAP);
}